// Round 11
// baseline (228.994 us; speedup 1.0000x reference)
//
#include <hip/hip_runtime.h>

#define NODES   304
#define BATCH   128
#define TSTEPS  20
#define HID     64
#define GCNIN   20
#define NN      (BATCH*NODES)      // 38912
#define NE      (NN*16)            // 622592
#define SEGSZ   (NN/4)             // 9728 (row-quarter for L2 phasing)
#define BCAP    64                 // bucket capacity per col
#define FC1_IN  (21*NODES)         // 6384
#define KP1     6400               // FC1_IN padded to /32
#define FC1_OUT 2048
#define FC2_OUT 300
#define NP2     304                // FC2_OUT padded to /16
#define BN_EPS  1e-5f

typedef __attribute__((ext_vector_type(8))) short short8;
typedef __attribute__((ext_vector_type(4))) float f32x4;
typedef __attribute__((ext_vector_type(2))) float f32x2;

static __device__ __forceinline__ short f2bf(float x) {
    unsigned u = __float_as_uint(x);
    unsigned r = (u + 0x7FFF + ((u >> 16) & 1)) >> 16;  // RNE
    return (short)r;
}
static __device__ __forceinline__ float bf2f(unsigned short v) {
    return __uint_as_float((unsigned)v << 16);
}

static __device__ __forceinline__ float fast_sigmoid(float q) {
    return __builtin_amdgcn_rcpf(1.f + __expf(-q));
}

// packed fp32 FMA (VOP3P)
static __device__ __forceinline__ f32x2 pk_fma(f32x2 a, f32x2 b, f32x2 c) {
    f32x2 d;
    asm("v_pk_fma_f32 %0, %1, %2, %3" : "=v"(d) : "v"(a), "v"(b), "v"(c));
    return d;
}

// DPP row_ror add (VALU pipe, no DS ops)
template <int C>
static __device__ __forceinline__ float dppadd(float v) {
    return v + __int_as_float(
        __builtin_amdgcn_update_dpp(0, __float_as_int(v), C, 0xF, 0xF, false));
}
static __device__ __forceinline__ float rsum16(float v) {
    v = dppadd<0x128>(v);
    v = dppadd<0x124>(v);
    v = dppadd<0x122>(v);
    v = dppadd<0x121>(v);
    return v;
}

// ---------------- bucketed edge build: ONE global atomic per edge ----------------
__global__ void k_bucket(const int* __restrict__ ei, const float* __restrict__ ew,
                         int* __restrict__ cnt, int2* __restrict__ bucket) {
    int e = blockIdx.x * blockDim.x + threadIdx.x;
    if (e < NE) {
        int c = ei[NE + e];
        int slot = atomicAdd(&cnt[c], 1);
        if (slot < BCAP) {
            int2 v;
            v.x = ei[e];
            v.y = __float_as_int(ew[e]);
            bucket[((size_t)c << 6) + slot] = v;
        }
    }
}

// ---- Xb = dinv * data_x as bf16 [NN][32] (64B rows); also computes dinv ----
__global__ __launch_bounds__(256) void k_cvtX(const float* __restrict__ X,
                                              const int* __restrict__ cnt,
                                              const int2* __restrict__ bucket,
                                              unsigned short* __restrict__ Xb,
                                              float* __restrict__ dinv) {
    int wv = threadIdx.x >> 5, f = threadIdx.x & 31;  // 8 nodes x 32 lanes
    int n = blockIdx.x * 8 + wv;
    __shared__ float rs[8][2];

    int2 e0 = bucket[((size_t)n << 6) + f];
    int2 e1 = bucket[((size_t)n << 6) + 32 + f];
    int deg = cnt[n];
    float xv = (f < GCNIN) ? X[(size_t)n * GCNIN + f] : 0.f;

    int dcap = deg < BCAP ? deg : BCAP;
    float s = ((f < dcap) ? __int_as_float(e0.y) : 0.f) +
              ((32 + f < dcap) ? __int_as_float(e1.y) : 0.f);
    s = rsum16(s);
    if ((f & 15) == 0) rs[wv][f >> 4] = s;
    __syncthreads();

    float dv = rsqrtf(fmaxf(1.f + rs[wv][0] + rs[wv][1], 1e-12f));
    if (f == 0) dinv[n] = dv;
    Xb[(size_t)n * 32 + f] = (f < GCNIN) ? (unsigned short)f2bf(xv * dv)
                                         : (unsigned short)0;
}

// ballot-partition the wave's staged edges by row-quarter (L2 phasing)
static __device__ __forceinline__ void stage_partition(
    int deg, int2 e, int f, int wv, int (*sIdx)[BCAP], float (*sWt)[BCAP],
    int& dcap) {
    dcap = deg < BCAP ? deg : BCAP;
    bool valid = f < dcap;
    int row = e.x;
    float w = __int_as_float(e.y);
    int q = (row >= SEGSZ) + (row >= 2 * SEGSZ) + (row >= 3 * SEGSZ);
    unsigned long long b0 = __ballot(valid && q == 0);
    unsigned long long b1 = __ballot(valid && q == 1);
    unsigned long long b2 = __ballot(valid && q == 2);
    unsigned long long b3 = __ballot(valid && q == 3);
    unsigned long long lmask = (1ULL << f) - 1;
    int pos = 0;
    if (q > 0) pos += __popcll(b0);
    if (q > 1) pos += __popcll(b1);
    if (q > 2) pos += __popcll(b2);
    unsigned long long mybal = (q == 0) ? b0 : (q == 1) ? b1 : (q == 2) ? b2 : b3;
    pos += __popcll(mybal & lmask);
    if (valid) {
        sIdx[wv][pos] = row;
        sWt[wv][pos] = w;
    }
}

// ---- layer0: gather RAW 20-dim feats (L2-resident 2.5MB table) + @W0 + BN +
//      ReLU + matvec @W1 -> h1 prescaled bf16 ----
__global__ __launch_bounds__(256) void k_gather20(const int* __restrict__ cnt,
                                                  const int2* __restrict__ bucket,
                                                  const float* __restrict__ dinv,
                                                  const unsigned short* __restrict__ Xb,
                                                  const float* __restrict__ W0,
                                                  const float* __restrict__ gb,
                                                  const float* __restrict__ bng,
                                                  const float* __restrict__ bnb,
                                                  const float* __restrict__ W1,
                                                  unsigned short* __restrict__ H1) {
    int wv = threadIdx.x >> 6, f = threadIdx.x & 63;
    int c = blockIdx.x * 4 + wv;
    int g = f >> 4, r = f & 15;  // edge-group, channel-pair lane
    __shared__ int sIdx[4][BCAP];
    __shared__ float sWt[4][BCAP];
    __shared__ float agg[4][32];
    __shared__ float xs[4][HID];

    int2 be = bucket[((size_t)c << 6) + f];
    int deg = cnt[c];
    float dc = dinv[c];
    unsigned selfv = *(const unsigned*)(Xb + (size_t)c * 32 + 2 * r);

    int dcap;
    stage_partition(deg, be, f, wv, sIdx, sWt, dcap);
    __syncthreads();

    f32x2 acc2;
    acc2[0] = 0.f;
    acc2[1] = 0.f;
    for (int base = 0; base < dcap; base += 16) {
        int idx[4];
        float w[4];
#pragma unroll
        for (int i = 0; i < 4; i++) {
            int l = base + (i << 2) + g;
            int lc = (l < dcap) ? l : dcap - 1;
            idx[i] = sIdx[wv][lc];
            w[i] = (l < dcap) ? sWt[wv][lc] : 0.f;
        }
        unsigned vv[4];
#pragma unroll
        for (int i = 0; i < 4; i++)
            vv[i] = *(const unsigned*)(Xb + (size_t)idx[i] * 32 + 2 * r);
#pragma unroll
        for (int i = 0; i < 4; i++) {
            acc2[0] = fmaf(bf2f((unsigned short)(vv[i] & 0xffff)), w[i], acc2[0]);
            acc2[1] = fmaf(bf2f((unsigned short)(vv[i] >> 16)), w[i], acc2[1]);
        }
    }
    acc2[0] += __shfl_xor(acc2[0], 16);
    acc2[0] += __shfl_xor(acc2[0], 32);
    acc2[1] += __shfl_xor(acc2[1], 16);
    acc2[1] += __shfl_xor(acc2[1], 32);
    if (g == 0) {
        agg[wv][2 * r] = acc2[0] + bf2f((unsigned short)(selfv & 0xffff));
        agg[wv][2 * r + 1] = acc2[1] + bf2f((unsigned short)(selfv >> 16));
    }
    __syncthreads();

    float v = 0.f;
#pragma unroll
    for (int k = 0; k < GCNIN; k++) v = fmaf(agg[wv][k], W0[k * HID + f], v);
    float scale = bng[f] * rsqrtf(1.f + BN_EPS);
    float y = fmaxf(fmaf(v * dc + gb[f], scale, bnb[f]), 0.f);

    xs[wv][f] = y;
    __syncthreads();
    float h = 0.f;
#pragma unroll
    for (int k4 = 0; k4 < HID / 4; k4++) {
        float4 xv = *(const float4*)&xs[wv][k4 * 4];
        h = fmaf(xv.x, W1[(k4 * 4 + 0) * HID + f], h);
        h = fmaf(xv.y, W1[(k4 * 4 + 1) * HID + f], h);
        h = fmaf(xv.z, W1[(k4 * 4 + 2) * HID + f], h);
        h = fmaf(xv.w, W1[(k4 * 4 + 3) * HID + f], h);
    }
    H1[(size_t)c * HID + f] = (unsigned short)f2bf(h * dc);  // pre-scaled
}

// -------- layer1 gather, channel-HALF (2.5MB line-set fits XCD L2) --------
template <int HALF>
__global__ __launch_bounds__(256) void k_gatherBh(const int* __restrict__ cnt,
                                                  const int2* __restrict__ bucket,
                                                  const float* __restrict__ dinv,
                                                  const unsigned short* __restrict__ H,
                                                  const float* __restrict__ gb,
                                                  const float* __restrict__ bng,
                                                  const float* __restrict__ bnb,
                                                  float* __restrict__ XO) {
    int wv = threadIdx.x >> 6, f = threadIdx.x & 63;
    int c = blockIdx.x * 4 + wv;
    int g = f >> 4, r = f & 15;  // edge-group, channel-pair lane
    int ch = HALF * 32 + 2 * r;
    __shared__ int sIdx[4][BCAP];
    __shared__ float sWt[4][BCAP];

    int2 be = bucket[((size_t)c << 6) + f];
    int deg = cnt[c];
    float dc = dinv[c];
    unsigned selfv = *(const unsigned*)(H + (size_t)c * HID + ch);

    int dcap;
    stage_partition(deg, be, f, wv, sIdx, sWt, dcap);
    __syncthreads();

    float a0 = 0.f, a1 = 0.f;
    for (int base = 0; base < dcap; base += 16) {
        int idx[4];
        float w[4];
#pragma unroll
        for (int i = 0; i < 4; i++) {
            int l = base + (i << 2) + g;
            int lc = (l < dcap) ? l : dcap - 1;
            idx[i] = sIdx[wv][lc];
            w[i] = (l < dcap) ? sWt[wv][lc] : 0.f;
        }
        unsigned hv[4];
#pragma unroll
        for (int i = 0; i < 4; i++)
            hv[i] = *(const unsigned*)(H + (size_t)idx[i] * HID + ch);
#pragma unroll
        for (int i = 0; i < 4; i++) {
            a0 = fmaf(bf2f((unsigned short)(hv[i] & 0xffff)), w[i], a0);
            a1 = fmaf(bf2f((unsigned short)(hv[i] >> 16)), w[i], a1);
        }
    }
    a0 += __shfl_xor(a0, 16);
    a0 += __shfl_xor(a0, 32);
    a1 += __shfl_xor(a1, 16);
    a1 += __shfl_xor(a1, 32);

    if (g == 0) {
        float rr = rsqrtf(1.f + BN_EPS);
        float2 o;
        o.x = fmaxf(fmaf((a0 + bf2f((unsigned short)(selfv & 0xffff))) * dc + gb[ch],
                         bng[ch] * rr, bnb[ch]), 0.f);
        o.y = fmaxf(fmaf((a1 + bf2f((unsigned short)(selfv >> 16))) * dc + gb[ch + 1],
                         bng[ch + 1] * rr, bnb[ch + 1]), 0.f);
        *(float2*)(XO + (size_t)c * HID + ch) = o;
    }
}

// ---------------- x2 [38912][64] -> x2t [64][38912] ----------------
__global__ __launch_bounds__(256) void k_xpose(const float* __restrict__ x2,
                                               float* __restrict__ x2t) {
    __shared__ float tile[64][65];
    int n0 = blockIdx.x * 64;
    for (int i = threadIdx.x; i < 4096; i += 256) {
        int r = i >> 6, h = i & 63;
        tile[r][h] = x2[(size_t)(n0 + r) * 64 + h];
    }
    __syncthreads();
    for (int i = threadIdx.x; i < 4096; i += 256) {
        int h = i >> 6, c = i & 63;
        x2t[(size_t)h * NN + n0 + c] = tile[c][h];
    }
}

// unpack 12 contiguous LDS floats (ch c0..c0+3 × 3 taps) into packed pairs
static __device__ __forceinline__ void load12(const float* base, f32x2 P[2][3]) {
    float4 f0 = *(const float4*)(base);
    float4 f1 = *(const float4*)(base + 4);
    float4 f2 = *(const float4*)(base + 8);
    P[0][0][0] = f0.x; P[0][0][1] = f0.w;
    P[0][1][0] = f0.y; P[0][1][1] = f1.x;
    P[0][2][0] = f0.z; P[0][2][1] = f1.y;
    P[1][0][0] = f1.z; P[1][0][1] = f2.y;
    P[1][1][0] = f1.w; P[1][1][1] = f2.z;
    P[1][2][0] = f2.x; P[1][2][1] = f2.w;
}

// ------- fused temporal, PHASE-SPLIT: conv1 fully into regs (ILP for trans
//         pipe), then pure-pk stage2. 16 pairs/block, 4 ch/lane ---------
__global__ __launch_bounds__(256) void k_temporal3(
    const float* __restrict__ data_x, const float* __restrict__ x2t,
    const float* __restrict__ w1, const float* __restrict__ b1,
    const float* __restrict__ w2, const float* __restrict__ b2,
    const float* __restrict__ w3, const float* __restrict__ b3,
    const float* __restrict__ v1, const float* __restrict__ vb1,
    const float* __restrict__ v2, const float* __restrict__ vb2,
    const float* __restrict__ v3, const float* __restrict__ vb3,
    const float* __restrict__ bn2g, const float* __restrict__ bn2b,
    short* __restrict__ Ab) {
    int bn0 = blockIdx.x * 16;
    int b = bn0 / NODES, node0 = bn0 % NODES;
    int tid = threadIdx.x;
    int p = tid >> 4;
    int c0 = (tid & 15) << 2;
    int node = node0 + p;

    __shared__ float xs[16][22];
    __shared__ float wlds[1344];

    if (tid < 192) {
        wlds[tid] = w1[tid];
        wlds[192 + tid] = w2[tid];
        wlds[384 + tid] = w3[tid];
        wlds[576 + tid] = v1[tid];
        wlds[768 + tid] = v2[tid];
        wlds[960 + tid] = v3[tid];
    }
    if (tid < 64) {
        wlds[1152 + tid] = b1[tid];
        wlds[1216 + tid] = b2[tid];
        wlds[1280 + tid] = b3[tid];
    }
    for (int i = tid; i < 320; i += 256) {
        int t = i >> 4, pp = i & 15;
        xs[pp][t + 1] = data_x[b * (TSTEPS * NODES) + t * NODES + node0 + pp];
    }
    if (tid < 16) { xs[tid][0] = 0.f; xs[tid][21] = 0.f; }

    float cb1 = vb1[0], cb2 = vb2[0], cb3 = vb3[0];
    float s2 = bn2g[node] * rsqrtf(1.f + BN_EPS);
    float bb2 = bn2b[node];
    short* dst = Ab + (size_t)b * KP1;

    __syncthreads();

    // ---- phase 1: conv1 for all 20 steps into registers (full ILP) ----
    f32x2 h[21][2];  // h[t][cp]; h[20] = gfeat
    {
        f32x2 A1p[2][3], A2p[2][3], A3p[2][3], B1p[2], B2p[2], B3p[2];
        load12(&wlds[0 + c0 * 3], A1p);
        load12(&wlds[192 + c0 * 3], A2p);
        load12(&wlds[384 + c0 * 3], A3p);
        {
            float4 t1 = *(const float4*)&wlds[1152 + c0];
            float4 t2 = *(const float4*)&wlds[1216 + c0];
            float4 t3 = *(const float4*)&wlds[1280 + c0];
            B1p[0][0] = t1.x; B1p[0][1] = t1.y; B1p[1][0] = t1.z; B1p[1][1] = t1.w;
            B2p[0][0] = t2.x; B2p[0][1] = t2.y; B2p[1][0] = t2.z; B2p[1][1] = t2.w;
            B3p[0][0] = t3.x; B3p[0][1] = t3.y; B3p[1][0] = t3.z; B3p[1][1] = t3.w;
        }
        f32x2 xp0, xp1;
        xp0[0] = xs[p][0]; xp0[1] = xs[p][0];
        xp1[0] = xs[p][1]; xp1[1] = xs[p][1];
#pragma unroll
        for (int t = 0; t < TSTEPS; t++) {
            float x2s = xs[p][t + 2];
            f32x2 xp2;
            xp2[0] = x2s; xp2[1] = x2s;
#pragma unroll
            for (int cp = 0; cp < 2; cp++) {
                f32x2 pv = pk_fma(A1p[cp][2], xp2,
                            pk_fma(A1p[cp][1], xp1, pk_fma(A1p[cp][0], xp0, B1p[cp])));
                f32x2 qv = pk_fma(A2p[cp][2], xp2,
                            pk_fma(A2p[cp][1], xp1, pk_fma(A2p[cp][0], xp0, B2p[cp])));
                f32x2 rv = pk_fma(A3p[cp][2], xp2,
                            pk_fma(A3p[cp][1], xp1, pk_fma(A3p[cp][0], xp0, B3p[cp])));
                h[t][cp][0] = fmaxf(fmaf(pv[0], fast_sigmoid(qv[0]), rv[0]), 0.f);
                h[t][cp][1] = fmaxf(fmaf(pv[1], fast_sigmoid(qv[1]), rv[1]), 0.f);
            }
            xp0 = xp1;
            xp1 = xp2;
        }
    }
    {
        const float4 gv = *(const float4*)(x2t + (size_t)(b >> 1) * NN +
                                           (b & 1) * (NODES * HID) + node * HID + c0);
        h[20][0][0] = fmaxf(gv.x, 0.f);
        h[20][0][1] = fmaxf(gv.y, 0.f);
        h[20][1][0] = fmaxf(gv.z, 0.f);
        h[20][1][1] = fmaxf(gv.w, 0.f);
    }

    // ---- phase 2: stage-2 conv + reduce + BN2d (U weights loaded now) ----
    f32x2 U1p[2][3], U2p[2][3], U3p[2][3];
    load12(&wlds[576 + c0 * 3], U1p);
    load12(&wlds[768 + c0 * 3], U2p);
    load12(&wlds[960 + c0 * 3], U3p);
    f32x2 zero2;
    zero2[0] = 0.f;
    zero2[1] = 0.f;

#pragma unroll
    for (int w = 0; w < 21; w++) {
        f32x2 pa = zero2, qa = zero2, ra = zero2;
#pragma unroll
        for (int cp = 0; cp < 2; cp++) {
            f32x2 hm = (w == 0) ? zero2 : h[w - 1][cp];
            f32x2 h0 = h[w][cp];
            f32x2 hp = (w == 20) ? zero2 : h[w + 1][cp];
            pa = pk_fma(U1p[cp][0], hm, pa);
            pa = pk_fma(U1p[cp][1], h0, pa);
            pa = pk_fma(U1p[cp][2], hp, pa);
            qa = pk_fma(U2p[cp][0], hm, qa);
            qa = pk_fma(U2p[cp][1], h0, qa);
            qa = pk_fma(U2p[cp][2], hp, qa);
            ra = pk_fma(U3p[cp][0], hm, ra);
            ra = pk_fma(U3p[cp][1], h0, ra);
            ra = pk_fma(U3p[cp][2], hp, ra);
        }
        float pp_ = rsum16(pa[0] + pa[1]);
        float qq_ = rsum16(qa[0] + qa[1]);
        float rr_ = rsum16(ra[0] + ra[1]);
        float P = pp_ + cb1, Q = qq_ + cb2, R = rr_ + cb3;
        float hv = fmaxf(fmaf(P, fast_sigmoid(Q), R), 0.f);
        if ((tid & 15) == 0) dst[w * NODES + node] = f2bf(fmaf(hv, s2, bb2));
    }
}

// ---------------- FC1 MFMA GEMM, B read directly from f32 fcW ----------------
#define KSPL1 8
#define KCH1  (KP1 / KSPL1)  // 800
__global__ __launch_bounds__(256) void k_gemm1f(const short* __restrict__ Ab,
                                                const float* __restrict__ fcW,
                                                float* __restrict__ part) {
    int lane = threadIdx.x & 63, wv = threadIdx.x >> 6;
    int r = lane & 15, kg = lane >> 4;
    int nb = blockIdx.x * 64, sp = blockIdx.y;

    f32x4 acc[2][4] = {};
    const short* a0 = Ab + (size_t)(wv * 32 + r) * KP1;
    const short* a1 = a0 + (size_t)16 * KP1;

    int k0 = sp * KCH1 + kg * 8;
    const float* wp = fcW + (size_t)k0 * FC1_OUT + nb + r;
    bool tailblk = (sp == KSPL1 - 1);

#pragma unroll 1
    for (int s = 0; s < KCH1 / 32; s++, k0 += 32) {
        short8 av0 = *(const short8*)(a0 + k0);
        short8 av1 = *(const short8*)(a1 + k0);
        short8 bv[4];
        if (tailblk && s == KCH1 / 32 - 1) {
#pragma unroll
            for (int f = 0; f < 4; f++)
#pragma unroll
                for (int i = 0; i < 8; i++) {
                    float v = (k0 + i < FC1_IN) ? wp[(size_t)i * FC1_OUT + f * 16] : 0.f;
                    bv[f][i] = f2bf(v);
                }
        } else {
#pragma unroll
            for (int f = 0; f < 4; f++)
#pragma unroll
                for (int i = 0; i < 8; i++)
                    bv[f][i] = f2bf(wp[(size_t)i * FC1_OUT + f * 16]);
        }
        acc[0][0] = __builtin_amdgcn_mfma_f32_16x16x32_bf16(av0, bv[0], acc[0][0], 0, 0, 0);
        acc[1][0] = __builtin_amdgcn_mfma_f32_16x16x32_bf16(av1, bv[0], acc[1][0], 0, 0, 0);
        acc[0][1] = __builtin_amdgcn_mfma_f32_16x16x32_bf16(av0, bv[1], acc[0][1], 0, 0, 0);
        acc[1][1] = __builtin_amdgcn_mfma_f32_16x16x32_bf16(av1, bv[1], acc[1][1], 0, 0, 0);
        acc[0][2] = __builtin_amdgcn_mfma_f32_16x16x32_bf16(av0, bv[2], acc[0][2], 0, 0, 0);
        acc[1][2] = __builtin_amdgcn_mfma_f32_16x16x32_bf16(av1, bv[2], acc[1][2], 0, 0, 0);
        acc[0][3] = __builtin_amdgcn_mfma_f32_16x16x32_bf16(av0, bv[3], acc[0][3], 0, 0, 0);
        acc[1][3] = __builtin_amdgcn_mfma_f32_16x16x32_bf16(av1, bv[3], acc[1][3], 0, 0, 0);
        wp += (size_t)32 * FC1_OUT;
    }

    float* dst = part + (size_t)sp * BATCH * FC1_OUT;
#pragma unroll
    for (int m = 0; m < 2; m++)
#pragma unroll
        for (int f = 0; f < 4; f++)
#pragma unroll
            for (int j = 0; j < 4; j++) {
                int row = wv * 32 + m * 16 + kg * 4 + j;
                int col = nb + f * 16 + r;
                dst[(size_t)row * FC1_OUT + col] = acc[m][f][j];
            }
}

// reduce split-K + bias + ReLU -> bf16 activations for FC2
__global__ __launch_bounds__(256) void k_reduce1(const float* __restrict__ part,
                                                 const float* __restrict__ bias,
                                                 short* __restrict__ Ab2) {
    int idx = blockIdx.x * 256 + threadIdx.x;
    int o = idx & (FC1_OUT - 1);
    float s = bias[o];
#pragma unroll
    for (int sp = 0; sp < KSPL1; sp++) s += part[(size_t)sp * BATCH * FC1_OUT + idx];
    Ab2[idx] = f2bf(fmaxf(s, 0.f));
}

// ---------------- FC2 MFMA GEMM, B read directly from f32 fc4W ----------------
#define KSPL2 8
#define KCH2  (FC1_OUT / KSPL2)  // 256
__global__ __launch_bounds__(256) void k_gemm2f(const short* __restrict__ Ab,
                                                const float* __restrict__ fc4W,
                                                float* __restrict__ part) {
    int lane = threadIdx.x & 63, wv = threadIdx.x >> 6;
    int r = lane & 15, kg = lane >> 4;
    int nb = blockIdx.x * 16, sp = blockIdx.y;

    f32x4 acc[2] = {};
    const short* a0 = Ab + (size_t)(wv * 32 + r) * FC1_OUT;
    const short* a1 = a0 + (size_t)16 * FC1_OUT;
    int col = nb + r;
    int colc = (col < FC2_OUT) ? col : FC2_OUT - 1;  // clamp; pad cols never read

    int k0 = sp * KCH2 + kg * 8;
    const float* wp = fc4W + (size_t)k0 * FC2_OUT + colc;
#pragma unroll 1
    for (int s = 0; s < KCH2 / 32; s++, k0 += 32) {
        short8 av0 = *(const short8*)(a0 + k0);
        short8 av1 = *(const short8*)(a1 + k0);
        short8 bv;
#pragma unroll
        for (int i = 0; i < 8; i++) bv[i] = f2bf(wp[(size_t)i * FC2_OUT]);
        acc[0] = __builtin_amdgcn_mfma_f32_16x16x32_bf16(av0, bv, acc[0], 0, 0, 0);
        acc[1] = __builtin_amdgcn_mfma_f32_16x16x32_bf16(av1, bv, acc[1], 0, 0, 0);
        wp += (size_t)32 * FC2_OUT;
    }

    float* dst = part + (size_t)sp * BATCH * NP2;
#pragma unroll
    for (int m = 0; m < 2; m++)
#pragma unroll
        for (int j = 0; j < 4; j++) {
            int row = wv * 32 + m * 16 + kg * 4 + j;
            dst[(size_t)row * NP2 + col] = acc[m][j];
        }
}

__global__ __launch_bounds__(256) void k_reduce2(const float* __restrict__ part,
                                                 const float* __restrict__ bias,
                                                 float* __restrict__ out) {
    int idx = blockIdx.x * 256 + threadIdx.x;
    if (idx >= BATCH * NP2) return;
    int b = idx / NP2, o = idx % NP2;
    float s = 0.f;
#pragma unroll
    for (int sp = 0; sp < KSPL2; sp++) s += part[(size_t)sp * BATCH * NP2 + idx];
    if (o < FC2_OUT) out[(size_t)b * FC2_OUT + o] = s + bias[o];
}

extern "C" void kernel_launch(void* const* d_in, const int* in_sizes, int n_in,
                              void* d_out, int out_size, void* d_ws, size_t ws_size,
                              hipStream_t stream) {
    const float* data_x = (const float*)d_in[0];
    const int* ei = (const int*)d_in[1];
    const float* ew = (const float*)d_in[2];
    const float* tc1w1 = (const float*)d_in[3];
    const float* tc1b1 = (const float*)d_in[4];
    const float* tc1w2 = (const float*)d_in[5];
    const float* tc1b2 = (const float*)d_in[6];
    const float* tc1w3 = (const float*)d_in[7];
    const float* tc1b3 = (const float*)d_in[8];
    const float* W0 = (const float*)d_in[9];
    const float* gb0 = (const float*)d_in[10];
    const float* bn0g = (const float*)d_in[11];
    const float* bn0b = (const float*)d_in[12];
    const float* W1 = (const float*)d_in[13];
    const float* gb1 = (const float*)d_in[14];
    const float* bn1g = (const float*)d_in[15];
    const float* bn1b = (const float*)d_in[16];
    const float* tc2w1 = (const float*)d_in[17];
    const float* tc2b1 = (const float*)d_in[18];
    const float* tc2w2 = (const float*)d_in[19];
    const float* tc2b2 = (const float*)d_in[20];
    const float* tc2w3 = (const float*)d_in[21];
    const float* tc2b3 = (const float*)d_in[22];
    const float* bn2g = (const float*)d_in[23];
    const float* bn2b = (const float*)d_in[24];
    const float* fcW = (const float*)d_in[25];
    const float* fcb = (const float*)d_in[26];
    const float* fc4W = (const float*)d_in[27];
    const float* fc4b = (const float*)d_in[28];
    float* out = (float*)d_out;

    char* ws = (char*)d_ws;
    // persistent: x2 (gfeat source) + Ab (FC1 bf16 activations)
    float* x2 = (float*)(ws + 0);                  // 9,961,472 B
    short* Ab = (short*)(ws + 9961472);            // 1,638,400 B
    const size_t ARENA = 9961472 + 1638400;        // 11,599,872

    // arena A (graph phase)
    size_t off = ARENA;
    auto alloc = [&](size_t bytes) -> void* {
        void* p = ws + off;
        off = (off + bytes + 255) & ~(size_t)255;
        return p;
    };
    int2* bucket = (int2*)alloc((size_t)NN * BCAP * 8);  // 19.9 MB
    int* cnt = (int*)alloc((size_t)NN * 4);
    float* dinv = (float*)alloc((size_t)NN * 4);
    unsigned short* Xb = (unsigned short*)alloc((size_t)NN * 32 * 2);  // 2.5 MB
    unsigned short* h1 = (unsigned short*)alloc((size_t)NN * HID * 2); // 5 MB

    // x2t overlaps arena A (bucket region dead after gatherB)
    float* x2t = (float*)(ws + ARENA);             // 9,961,472 B

    // arena C (FC phase) — overlaps arena A and x2t, used only after temporal
    off = ARENA;
    float* part1 = (float*)alloc((size_t)KSPL1 * BATCH * FC1_OUT * 4);
    short* Ab2 = (short*)alloc((size_t)BATCH * FC1_OUT * 2);
    float* part2 = (float*)alloc((size_t)KSPL2 * BATCH * NP2 * 4);
    (void)ws_size; (void)in_sizes; (void)n_in; (void)out_size;

    // ---- bucketed edge build ----
    hipMemsetAsync(cnt, 0, (size_t)NN * 4, stream);
    k_bucket<<<(NE + 255) / 256, 256, 0, stream>>>(ei, ew, cnt, bucket);

    // ---- GCN ----
    k_cvtX<<<NN / 8, 256, 0, stream>>>(data_x, cnt, bucket, Xb, dinv);
    k_gather20<<<NN / 4, 256, 0, stream>>>(cnt, bucket, dinv, Xb, W0, gb0, bn0g,
                                           bn0b, W1, h1);
    k_gatherBh<0><<<NN / 4, 256, 0, stream>>>(cnt, bucket, dinv, h1, gb1, bn1g,
                                              bn1b, x2);
    k_gatherBh<1><<<NN / 4, 256, 0, stream>>>(cnt, bucket, dinv, h1, gb1, bn1g,
                                              bn1b, x2);

    // ---- transpose x2 for coalesced gfeat ----
    k_xpose<<<NN / 64, 256, 0, stream>>>(x2, x2t);

    // ---- temporal (phase-split, packed fp32) -> bf16 Ab ----
    hipMemsetAsync(Ab, 0, (size_t)BATCH * KP1 * 2, stream);  // zero K-padding
    k_temporal3<<<NN / 16, 256, 0, stream>>>(data_x, x2t, tc1w1, tc1b1, tc1w2, tc1b2,
                                             tc1w3, tc1b3, tc2w1, tc2b1, tc2w2, tc2b2,
                                             tc2w3, tc2b3, bn2g, bn2b, Ab);

    // ---- FC (bf16 MFMA) ----
    {
        dim3 g(FC1_OUT / 64, KSPL1);
        k_gemm1f<<<g, 256, 0, stream>>>(Ab, fcW, part1);
    }
    k_reduce1<<<BATCH * FC1_OUT / 256, 256, 0, stream>>>(part1, fcb, Ab2);
    {
        dim3 g(NP2 / 16, KSPL2);
        k_gemm2f<<<g, 256, 0, stream>>>(Ab2, fc4W, part2);
    }
    k_reduce2<<<(BATCH * NP2 + 255) / 256, 256, 0, stream>>>(part2, fc4b, out);
}

// Round 12
// 184.910 us; speedup vs baseline: 1.2384x; 1.2384x over previous
//
#include <hip/hip_runtime.h>

#define NODES   304
#define BATCH   128
#define TSTEPS  20
#define HID     64
#define GCNIN   20
#define NN      (BATCH*NODES)      // 38912
#define NE      (NN*16)            // 622592
#define SEGSZ   (NN/4)             // 9728 (row-quarter for L2 phasing)
#define BCAP    64                 // bucket capacity per col
#define FC1_IN  (21*NODES)         // 6384
#define KP1     6400               // FC1_IN padded to /32
#define FC1_OUT 2048
#define FC2_OUT 300
#define NP2     304                // FC2_OUT padded to /16
#define BN_EPS  1e-5f

typedef __attribute__((ext_vector_type(8))) short short8;
typedef __attribute__((ext_vector_type(4))) float f32x4;
typedef __attribute__((ext_vector_type(2))) float f32x2;

static __device__ __forceinline__ short f2bf(float x) {
    unsigned u = __float_as_uint(x);
    unsigned r = (u + 0x7FFF + ((u >> 16) & 1)) >> 16;  // RNE
    return (short)r;
}
static __device__ __forceinline__ float bf2f(unsigned short v) {
    return __uint_as_float((unsigned)v << 16);
}

static __device__ __forceinline__ float fast_sigmoid(float q) {
    return __builtin_amdgcn_rcpf(1.f + __expf(-q));
}

// packed fp32 FMA (VOP3P)
static __device__ __forceinline__ f32x2 pk_fma(f32x2 a, f32x2 b, f32x2 c) {
    f32x2 d;
    asm("v_pk_fma_f32 %0, %1, %2, %3" : "=v"(d) : "v"(a), "v"(b), "v"(c));
    return d;
}

// DPP row_ror add (VALU pipe, no DS ops)
template <int C>
static __device__ __forceinline__ float dppadd(float v) {
    return v + __int_as_float(
        __builtin_amdgcn_update_dpp(0, __float_as_int(v), C, 0xF, 0xF, false));
}
static __device__ __forceinline__ float rsum16(float v) {
    v = dppadd<0x128>(v);
    v = dppadd<0x124>(v);
    v = dppadd<0x122>(v);
    v = dppadd<0x121>(v);
    return v;
}

// ------- bucketed edge build: ONE global atomic/edge; packed u32 entries -------
// entry = (bf16(weight) << 16) | row16   (row < 38912 < 65536)
__global__ void k_bucket(const int* __restrict__ ei, const float* __restrict__ ew,
                         int* __restrict__ cnt, unsigned* __restrict__ bucket) {
    int e = blockIdx.x * blockDim.x + threadIdx.x;
    if (e < NE) {
        int c = ei[NE + e];
        int slot = atomicAdd(&cnt[c], 1);
        if (slot < BCAP) {
            unsigned v = ((unsigned)(unsigned short)f2bf(ew[e]) << 16) |
                         (unsigned)ei[e];
            bucket[((size_t)c << 6) + slot] = v;
        }
    }
}

// ---- Xb = dinv * data_x as bf16 [NN][32] (64B rows); also computes dinv ----
__global__ __launch_bounds__(256) void k_cvtX(const float* __restrict__ X,
                                              const int* __restrict__ cnt,
                                              const unsigned* __restrict__ bucket,
                                              unsigned short* __restrict__ Xb,
                                              float* __restrict__ dinv) {
    int wv = threadIdx.x >> 5, f = threadIdx.x & 31;  // 8 nodes x 32 lanes
    int n = blockIdx.x * 8 + wv;
    __shared__ float rs[8][2];

    unsigned e0 = bucket[((size_t)n << 6) + f];
    unsigned e1 = bucket[((size_t)n << 6) + 32 + f];
    int deg = cnt[n];
    float xv = (f < GCNIN) ? X[(size_t)n * GCNIN + f] : 0.f;

    int dcap = deg < BCAP ? deg : BCAP;
    float s = ((f < dcap) ? bf2f((unsigned short)(e0 >> 16)) : 0.f) +
              ((32 + f < dcap) ? bf2f((unsigned short)(e1 >> 16)) : 0.f);
    s = rsum16(s);
    if ((f & 15) == 0) rs[wv][f >> 4] = s;
    __syncthreads();

    float dv = rsqrtf(fmaxf(1.f + rs[wv][0] + rs[wv][1], 1e-12f));
    if (f == 0) dinv[n] = dv;
    Xb[(size_t)n * 32 + f] = (f < GCNIN) ? (unsigned short)f2bf(xv * dv)
                                         : (unsigned short)0;
}

// ballot-partition the wave's staged edges by row-quarter (L2 phasing)
static __device__ __forceinline__ void stage_partition(
    int deg, unsigned e, int f, int wv, int (*sIdx)[BCAP], float (*sWt)[BCAP],
    int& dcap) {
    dcap = deg < BCAP ? deg : BCAP;
    bool valid = f < dcap;
    int row = (int)(e & 0xffffu);
    float w = bf2f((unsigned short)(e >> 16));
    int q = (row >= SEGSZ) + (row >= 2 * SEGSZ) + (row >= 3 * SEGSZ);
    unsigned long long b0 = __ballot(valid && q == 0);
    unsigned long long b1 = __ballot(valid && q == 1);
    unsigned long long b2 = __ballot(valid && q == 2);
    unsigned long long b3 = __ballot(valid && q == 3);
    unsigned long long lmask = (1ULL << f) - 1;
    int pos = 0;
    if (q > 0) pos += __popcll(b0);
    if (q > 1) pos += __popcll(b1);
    if (q > 2) pos += __popcll(b2);
    unsigned long long mybal = (q == 0) ? b0 : (q == 1) ? b1 : (q == 2) ? b2 : b3;
    pos += __popcll(mybal & lmask);
    if (valid) {
        sIdx[wv][pos] = row;
        sWt[wv][pos] = w;
    }
}

// ---- layer0: gather RAW 20-dim feats (L2-resident 2.5MB table) + @W0 + BN +
//      ReLU + matvec @W1 -> h1 prescaled bf16 ----
__global__ __launch_bounds__(256) void k_gather20(const int* __restrict__ cnt,
                                                  const unsigned* __restrict__ bucket,
                                                  const float* __restrict__ dinv,
                                                  const unsigned short* __restrict__ Xb,
                                                  const float* __restrict__ W0,
                                                  const float* __restrict__ gb,
                                                  const float* __restrict__ bng,
                                                  const float* __restrict__ bnb,
                                                  const float* __restrict__ W1,
                                                  unsigned short* __restrict__ H1) {
    int wv = threadIdx.x >> 6, f = threadIdx.x & 63;
    int c = blockIdx.x * 4 + wv;
    int g = f >> 4, r = f & 15;  // edge-group, channel-pair lane
    __shared__ int sIdx[4][BCAP];
    __shared__ float sWt[4][BCAP];
    __shared__ float agg[4][32];
    __shared__ float xs[4][HID];

    unsigned be = bucket[((size_t)c << 6) + f];
    int deg = cnt[c];
    float dc = dinv[c];
    unsigned selfv = *(const unsigned*)(Xb + (size_t)c * 32 + 2 * r);

    int dcap;
    stage_partition(deg, be, f, wv, sIdx, sWt, dcap);
    __syncthreads();

    f32x2 acc2;
    acc2[0] = 0.f;
    acc2[1] = 0.f;
    for (int base = 0; base < dcap; base += 16) {
        int idx[4];
        float w[4];
#pragma unroll
        for (int i = 0; i < 4; i++) {
            int l = base + (i << 2) + g;
            int lc = (l < dcap) ? l : dcap - 1;
            idx[i] = sIdx[wv][lc];
            w[i] = (l < dcap) ? sWt[wv][lc] : 0.f;
        }
        unsigned vv[4];
#pragma unroll
        for (int i = 0; i < 4; i++)
            vv[i] = *(const unsigned*)(Xb + (size_t)idx[i] * 32 + 2 * r);
#pragma unroll
        for (int i = 0; i < 4; i++) {
            acc2[0] = fmaf(bf2f((unsigned short)(vv[i] & 0xffff)), w[i], acc2[0]);
            acc2[1] = fmaf(bf2f((unsigned short)(vv[i] >> 16)), w[i], acc2[1]);
        }
    }
    acc2[0] += __shfl_xor(acc2[0], 16);
    acc2[0] += __shfl_xor(acc2[0], 32);
    acc2[1] += __shfl_xor(acc2[1], 16);
    acc2[1] += __shfl_xor(acc2[1], 32);
    if (g == 0) {
        agg[wv][2 * r] = acc2[0] + bf2f((unsigned short)(selfv & 0xffff));
        agg[wv][2 * r + 1] = acc2[1] + bf2f((unsigned short)(selfv >> 16));
    }
    __syncthreads();

    float v = 0.f;
#pragma unroll
    for (int k = 0; k < GCNIN; k++) v = fmaf(agg[wv][k], W0[k * HID + f], v);
    float scale = bng[f] * rsqrtf(1.f + BN_EPS);
    float y = fmaxf(fmaf(v * dc + gb[f], scale, bnb[f]), 0.f);

    xs[wv][f] = y;
    __syncthreads();
    float h = 0.f;
#pragma unroll
    for (int k4 = 0; k4 < HID / 4; k4++) {
        float4 xv = *(const float4*)&xs[wv][k4 * 4];
        h = fmaf(xv.x, W1[(k4 * 4 + 0) * HID + f], h);
        h = fmaf(xv.y, W1[(k4 * 4 + 1) * HID + f], h);
        h = fmaf(xv.z, W1[(k4 * 4 + 2) * HID + f], h);
        h = fmaf(xv.w, W1[(k4 * 4 + 3) * HID + f], h);
    }
    H1[(size_t)c * HID + f] = (unsigned short)f2bf(h * dc);  // pre-scaled
}

// -------- layer1 gather (ushort4 loads, 4 edge-groups) + BN + ReLU -> x2 f32 -----
__global__ __launch_bounds__(256) void k_gatherB(const int* __restrict__ cnt,
                                                 const unsigned* __restrict__ bucket,
                                                 const float* __restrict__ dinv,
                                                 const unsigned short* __restrict__ H,
                                                 const float* __restrict__ gb,
                                                 const float* __restrict__ bng,
                                                 const float* __restrict__ bnb,
                                                 float* __restrict__ XO) {
    int wv = threadIdx.x >> 6, f = threadIdx.x & 63;
    int c = blockIdx.x * 4 + wv;
    int g = f >> 4, r = f & 15;  // edge-group, channel-quad lane
    __shared__ int sIdx[4][BCAP];
    __shared__ float sWt[4][BCAP];

    unsigned be = bucket[((size_t)c << 6) + f];
    int deg = cnt[c];
    float dc = dinv[c];
    ushort4 selfv = *(const ushort4*)(H + (size_t)c * HID + 4 * r);

    int dcap;
    stage_partition(deg, be, f, wv, sIdx, sWt, dcap);
    __syncthreads();

    float a0 = 0.f, a1 = 0.f, a2 = 0.f, a3 = 0.f;
    for (int base = 0; base < dcap; base += 16) {
        int idx[4];
        float w[4];
#pragma unroll
        for (int i = 0; i < 4; i++) {
            int l = base + (i << 2) + g;
            int lc = (l < dcap) ? l : dcap - 1;
            idx[i] = sIdx[wv][lc];
            w[i] = (l < dcap) ? sWt[wv][lc] : 0.f;
        }
        ushort4 hv[4];
#pragma unroll
        for (int i = 0; i < 4; i++)
            hv[i] = *(const ushort4*)(H + (size_t)idx[i] * HID + 4 * r);
#pragma unroll
        for (int i = 0; i < 4; i++) {
            a0 = fmaf(bf2f(hv[i].x), w[i], a0);
            a1 = fmaf(bf2f(hv[i].y), w[i], a1);
            a2 = fmaf(bf2f(hv[i].z), w[i], a2);
            a3 = fmaf(bf2f(hv[i].w), w[i], a3);
        }
    }
    a0 += __shfl_xor(a0, 16); a0 += __shfl_xor(a0, 32);
    a1 += __shfl_xor(a1, 16); a1 += __shfl_xor(a1, 32);
    a2 += __shfl_xor(a2, 16); a2 += __shfl_xor(a2, 32);
    a3 += __shfl_xor(a3, 16); a3 += __shfl_xor(a3, 32);

    if (g == 0) {
        float4 scv = *(const float4*)&bng[4 * r];
        float4 bbv = *(const float4*)&bnb[4 * r];
        float4 gbv = *(const float4*)&gb[4 * r];
        float rr = rsqrtf(1.f + BN_EPS);
        float4 o;
        o.x = fmaxf(fmaf((a0 + bf2f(selfv.x)) * dc + gbv.x, scv.x * rr, bbv.x), 0.f);
        o.y = fmaxf(fmaf((a1 + bf2f(selfv.y)) * dc + gbv.y, scv.y * rr, bbv.y), 0.f);
        o.z = fmaxf(fmaf((a2 + bf2f(selfv.z)) * dc + gbv.z, scv.z * rr, bbv.z), 0.f);
        o.w = fmaxf(fmaf((a3 + bf2f(selfv.w)) * dc + gbv.w, scv.w * rr, bbv.w), 0.f);
        *(float4*)(XO + (size_t)c * HID + 4 * r) = o;
    }
}

// ---------------- x2 [38912][64] -> x2t [64][38912] ----------------
__global__ __launch_bounds__(256) void k_xpose(const float* __restrict__ x2,
                                               float* __restrict__ x2t) {
    __shared__ float tile[64][65];
    int n0 = blockIdx.x * 64;
    for (int i = threadIdx.x; i < 4096; i += 256) {
        int r = i >> 6, h = i & 63;
        tile[r][h] = x2[(size_t)(n0 + r) * 64 + h];
    }
    __syncthreads();
    for (int i = threadIdx.x; i < 4096; i += 256) {
        int h = i >> 6, c = i & 63;
        x2t[(size_t)h * NN + n0 + c] = tile[c][h];
    }
}

// unpack 12 contiguous LDS floats (ch c0..c0+3 × 3 taps) into packed pairs
static __device__ __forceinline__ void load12(const float* base, f32x2 P[2][3]) {
    float4 f0 = *(const float4*)(base);
    float4 f1 = *(const float4*)(base + 4);
    float4 f2 = *(const float4*)(base + 8);
    P[0][0][0] = f0.x; P[0][0][1] = f0.w;
    P[0][1][0] = f0.y; P[0][1][1] = f1.x;
    P[0][2][0] = f0.z; P[0][2][1] = f1.y;
    P[1][0][0] = f1.z; P[1][0][1] = f2.y;
    P[1][1][0] = f1.w; P[1][1][1] = f2.z;
    P[1][2][0] = f2.x; P[1][2][1] = f2.w;
}

// ---------------- fused temporal: packed-fp32, LDS weights, 16 pairs/block ----
// (R10 rolling-window version — measured best: 48 µs, 64 VGPR, Occ 31%)
__global__ __launch_bounds__(256) void k_temporal2(
    const float* __restrict__ data_x, const float* __restrict__ x2t,
    const float* __restrict__ w1, const float* __restrict__ b1,
    const float* __restrict__ w2, const float* __restrict__ b2,
    const float* __restrict__ w3, const float* __restrict__ b3,
    const float* __restrict__ v1, const float* __restrict__ vb1,
    const float* __restrict__ v2, const float* __restrict__ vb2,
    const float* __restrict__ v3, const float* __restrict__ vb3,
    const float* __restrict__ bn2g, const float* __restrict__ bn2b,
    short* __restrict__ Ab) {
    int bn0 = blockIdx.x * 16;
    int b = bn0 / NODES, node0 = bn0 % NODES;
    int tid = threadIdx.x;
    int p = tid >> 4;
    int c0 = (tid & 15) << 2;
    int node = node0 + p;

    __shared__ float xs[16][22];
    __shared__ float wlds[1344];

    if (tid < 192) {
        wlds[tid] = w1[tid];
        wlds[192 + tid] = w2[tid];
        wlds[384 + tid] = w3[tid];
        wlds[576 + tid] = v1[tid];
        wlds[768 + tid] = v2[tid];
        wlds[960 + tid] = v3[tid];
    }
    if (tid < 64) {
        wlds[1152 + tid] = b1[tid];
        wlds[1216 + tid] = b2[tid];
        wlds[1280 + tid] = b3[tid];
    }
    for (int i = tid; i < 320; i += 256) {
        int t = i >> 4, pp = i & 15;
        xs[pp][t + 1] = data_x[b * (TSTEPS * NODES) + t * NODES + node0 + pp];
    }
    if (tid < 16) { xs[tid][0] = 0.f; xs[tid][21] = 0.f; }

    float cb1 = vb1[0], cb2 = vb2[0], cb3 = vb3[0];
    float s2 = bn2g[node] * rsqrtf(1.f + BN_EPS);
    float bb2 = bn2b[node];
    short* dst = Ab + (size_t)b * KP1;

    __syncthreads();

    f32x2 A1p[2][3], A2p[2][3], A3p[2][3], B1p[2], B2p[2], B3p[2];
    f32x2 U1p[2][3], U2p[2][3], U3p[2][3];
    load12(&wlds[0 + c0 * 3], A1p);
    load12(&wlds[192 + c0 * 3], A2p);
    load12(&wlds[384 + c0 * 3], A3p);
    load12(&wlds[576 + c0 * 3], U1p);
    load12(&wlds[768 + c0 * 3], U2p);
    load12(&wlds[960 + c0 * 3], U3p);
    {
        float4 t1 = *(const float4*)&wlds[1152 + c0];
        float4 t2 = *(const float4*)&wlds[1216 + c0];
        float4 t3 = *(const float4*)&wlds[1280 + c0];
        B1p[0][0] = t1.x; B1p[0][1] = t1.y; B1p[1][0] = t1.z; B1p[1][1] = t1.w;
        B2p[0][0] = t2.x; B2p[0][1] = t2.y; B2p[1][0] = t2.z; B2p[1][1] = t2.w;
        B3p[0][0] = t3.x; B3p[0][1] = t3.y; B3p[1][0] = t3.z; B3p[1][1] = t3.w;
    }

    f32x2 hA2[2] = {}, hB2[2] = {}, hC2[2];
    float xr0 = xs[p][0], xr1 = xs[p][1];

#pragma unroll
    for (int j = 0; j <= 21; j++) {
        if (j < 20) {
            float xr2 = xs[p][j + 2];
            f32x2 x0d, x1d, x2d;
            x0d[0] = xr0; x0d[1] = xr0;
            x1d[0] = xr1; x1d[1] = xr1;
            x2d[0] = xr2; x2d[1] = xr2;
#pragma unroll
            for (int cp = 0; cp < 2; cp++) {
                f32x2 pv = pk_fma(A1p[cp][2], x2d,
                            pk_fma(A1p[cp][1], x1d, pk_fma(A1p[cp][0], x0d, B1p[cp])));
                f32x2 qv = pk_fma(A2p[cp][2], x2d,
                            pk_fma(A2p[cp][1], x1d, pk_fma(A2p[cp][0], x0d, B2p[cp])));
                f32x2 rv = pk_fma(A3p[cp][2], x2d,
                            pk_fma(A3p[cp][1], x1d, pk_fma(A3p[cp][0], x0d, B3p[cp])));
                hC2[cp][0] = fmaxf(fmaf(pv[0], fast_sigmoid(qv[0]), rv[0]), 0.f);
                hC2[cp][1] = fmaxf(fmaf(pv[1], fast_sigmoid(qv[1]), rv[1]), 0.f);
            }
            xr0 = xr1;
            xr1 = xr2;
        } else if (j == 20) {
            const float4 gv = *(const float4*)(x2t + (size_t)(b >> 1) * NN +
                                               (b & 1) * (NODES * HID) + node * HID + c0);
            hC2[0][0] = fmaxf(gv.x, 0.f);
            hC2[0][1] = fmaxf(gv.y, 0.f);
            hC2[1][0] = fmaxf(gv.z, 0.f);
            hC2[1][1] = fmaxf(gv.w, 0.f);
        } else {
            hC2[0][0] = 0.f; hC2[0][1] = 0.f;
            hC2[1][0] = 0.f; hC2[1][1] = 0.f;
        }
        if (j >= 1) {
            int w = j - 1;
            f32x2 pa, qa, ra;
            pa[0] = 0.f; pa[1] = 0.f;
            qa[0] = 0.f; qa[1] = 0.f;
            ra[0] = 0.f; ra[1] = 0.f;
#pragma unroll
            for (int cp = 0; cp < 2; cp++) {
                pa = pk_fma(U1p[cp][0], hA2[cp], pa);
                pa = pk_fma(U1p[cp][1], hB2[cp], pa);
                pa = pk_fma(U1p[cp][2], hC2[cp], pa);
                qa = pk_fma(U2p[cp][0], hA2[cp], qa);
                qa = pk_fma(U2p[cp][1], hB2[cp], qa);
                qa = pk_fma(U2p[cp][2], hC2[cp], qa);
                ra = pk_fma(U3p[cp][0], hA2[cp], ra);
                ra = pk_fma(U3p[cp][1], hB2[cp], ra);
                ra = pk_fma(U3p[cp][2], hC2[cp], ra);
            }
            float pp_ = rsum16(pa[0] + pa[1]);
            float qq_ = rsum16(qa[0] + qa[1]);
            float rr_ = rsum16(ra[0] + ra[1]);
            float P = pp_ + cb1, Q = qq_ + cb2, R = rr_ + cb3;
            float hv = fmaxf(fmaf(P, fast_sigmoid(Q), R), 0.f);
            if ((tid & 15) == 0) dst[w * NODES + node] = f2bf(fmaf(hv, s2, bb2));
        }
        hA2[0] = hB2[0]; hA2[1] = hB2[1];
        hB2[0] = hC2[0]; hB2[1] = hC2[1];
    }
}

// ---------------- FC1 MFMA GEMM, B read directly from f32 fcW ----------------
#define KSPL1 8
#define KCH1  (KP1 / KSPL1)  // 800
__global__ __launch_bounds__(256) void k_gemm1f(const short* __restrict__ Ab,
                                                const float* __restrict__ fcW,
                                                float* __restrict__ part) {
    int lane = threadIdx.x & 63, wv = threadIdx.x >> 6;
    int r = lane & 15, kg = lane >> 4;
    int nb = blockIdx.x * 64, sp = blockIdx.y;

    f32x4 acc[2][4] = {};
    const short* a0 = Ab + (size_t)(wv * 32 + r) * KP1;
    const short* a1 = a0 + (size_t)16 * KP1;

    int k0 = sp * KCH1 + kg * 8;
    const float* wp = fcW + (size_t)k0 * FC1_OUT + nb + r;
    bool tailblk = (sp == KSPL1 - 1);

#pragma unroll 1
    for (int s = 0; s < KCH1 / 32; s++, k0 += 32) {
        short8 av0 = *(const short8*)(a0 + k0);
        short8 av1 = *(const short8*)(a1 + k0);
        short8 bv[4];
        if (tailblk && s == KCH1 / 32 - 1) {
#pragma unroll
            for (int f = 0; f < 4; f++)
#pragma unroll
                for (int i = 0; i < 8; i++) {
                    float v = (k0 + i < FC1_IN) ? wp[(size_t)i * FC1_OUT + f * 16] : 0.f;
                    bv[f][i] = f2bf(v);
                }
        } else {
#pragma unroll
            for (int f = 0; f < 4; f++)
#pragma unroll
                for (int i = 0; i < 8; i++)
                    bv[f][i] = f2bf(wp[(size_t)i * FC1_OUT + f * 16]);
        }
        acc[0][0] = __builtin_amdgcn_mfma_f32_16x16x32_bf16(av0, bv[0], acc[0][0], 0, 0, 0);
        acc[1][0] = __builtin_amdgcn_mfma_f32_16x16x32_bf16(av1, bv[0], acc[1][0], 0, 0, 0);
        acc[0][1] = __builtin_amdgcn_mfma_f32_16x16x32_bf16(av0, bv[1], acc[0][1], 0, 0, 0);
        acc[1][1] = __builtin_amdgcn_mfma_f32_16x16x32_bf16(av1, bv[1], acc[1][1], 0, 0, 0);
        acc[0][2] = __builtin_amdgcn_mfma_f32_16x16x32_bf16(av0, bv[2], acc[0][2], 0, 0, 0);
        acc[1][2] = __builtin_amdgcn_mfma_f32_16x16x32_bf16(av1, bv[2], acc[1][2], 0, 0, 0);
        acc[0][3] = __builtin_amdgcn_mfma_f32_16x16x32_bf16(av0, bv[3], acc[0][3], 0, 0, 0);
        acc[1][3] = __builtin_amdgcn_mfma_f32_16x16x32_bf16(av1, bv[3], acc[1][3], 0, 0, 0);
        wp += (size_t)32 * FC1_OUT;
    }

    float* dst = part + (size_t)sp * BATCH * FC1_OUT;
#pragma unroll
    for (int m = 0; m < 2; m++)
#pragma unroll
        for (int f = 0; f < 4; f++)
#pragma unroll
            for (int j = 0; j < 4; j++) {
                int row = wv * 32 + m * 16 + kg * 4 + j;
                int col = nb + f * 16 + r;
                dst[(size_t)row * FC1_OUT + col] = acc[m][f][j];
            }
}

// reduce split-K + bias + ReLU -> bf16 activations for FC2
__global__ __launch_bounds__(256) void k_reduce1(const float* __restrict__ part,
                                                 const float* __restrict__ bias,
                                                 short* __restrict__ Ab2) {
    int idx = blockIdx.x * 256 + threadIdx.x;
    int o = idx & (FC1_OUT - 1);
    float s = bias[o];
#pragma unroll
    for (int sp = 0; sp < KSPL1; sp++) s += part[(size_t)sp * BATCH * FC1_OUT + idx];
    Ab2[idx] = f2bf(fmaxf(s, 0.f));
}

// ---------------- FC2 MFMA GEMM, B read directly from f32 fc4W ----------------
#define KSPL2 8
#define KCH2  (FC1_OUT / KSPL2)  // 256
__global__ __launch_bounds__(256) void k_gemm2f(const short* __restrict__ Ab,
                                                const float* __restrict__ fc4W,
                                                float* __restrict__ part) {
    int lane = threadIdx.x & 63, wv = threadIdx.x >> 6;
    int r = lane & 15, kg = lane >> 4;
    int nb = blockIdx.x * 16, sp = blockIdx.y;

    f32x4 acc[2] = {};
    const short* a0 = Ab + (size_t)(wv * 32 + r) * FC1_OUT;
    const short* a1 = a0 + (size_t)16 * FC1_OUT;
    int col = nb + r;
    int colc = (col < FC2_OUT) ? col : FC2_OUT - 1;  // clamp; pad cols never read

    int k0 = sp * KCH2 + kg * 8;
    const float* wp = fc4W + (size_t)k0 * FC2_OUT + colc;
#pragma unroll 1
    for (int s = 0; s < KCH2 / 32; s++, k0 += 32) {
        short8 av0 = *(const short8*)(a0 + k0);
        short8 av1 = *(const short8*)(a1 + k0);
        short8 bv;
#pragma unroll
        for (int i = 0; i < 8; i++) bv[i] = f2bf(wp[(size_t)i * FC2_OUT]);
        acc[0] = __builtin_amdgcn_mfma_f32_16x16x32_bf16(av0, bv, acc[0], 0, 0, 0);
        acc[1] = __builtin_amdgcn_mfma_f32_16x16x32_bf16(av1, bv, acc[1], 0, 0, 0);
        wp += (size_t)32 * FC2_OUT;
    }

    float* dst = part + (size_t)sp * BATCH * NP2;
#pragma unroll
    for (int m = 0; m < 2; m++)
#pragma unroll
        for (int j = 0; j < 4; j++) {
            int row = wv * 32 + m * 16 + kg * 4 + j;
            dst[(size_t)row * NP2 + col] = acc[m][j];
        }
}

__global__ __launch_bounds__(256) void k_reduce2(const float* __restrict__ part,
                                                 const float* __restrict__ bias,
                                                 float* __restrict__ out) {
    int idx = blockIdx.x * 256 + threadIdx.x;
    if (idx >= BATCH * NP2) return;
    int b = idx / NP2, o = idx % NP2;
    float s = 0.f;
#pragma unroll
    for (int sp = 0; sp < KSPL2; sp++) s += part[(size_t)sp * BATCH * NP2 + idx];
    if (o < FC2_OUT) out[(size_t)b * FC2_OUT + o] = s + bias[o];
}

extern "C" void kernel_launch(void* const* d_in, const int* in_sizes, int n_in,
                              void* d_out, int out_size, void* d_ws, size_t ws_size,
                              hipStream_t stream) {
    const float* data_x = (const float*)d_in[0];
    const int* ei = (const int*)d_in[1];
    const float* ew = (const float*)d_in[2];
    const float* tc1w1 = (const float*)d_in[3];
    const float* tc1b1 = (const float*)d_in[4];
    const float* tc1w2 = (const float*)d_in[5];
    const float* tc1b2 = (const float*)d_in[6];
    const float* tc1w3 = (const float*)d_in[7];
    const float* tc1b3 = (const float*)d_in[8];
    const float* W0 = (const float*)d_in[9];
    const float* gb0 = (const float*)d_in[10];
    const float* bn0g = (const float*)d_in[11];
    const float* bn0b = (const float*)d_in[12];
    const float* W1 = (const float*)d_in[13];
    const float* gb1 = (const float*)d_in[14];
    const float* bn1g = (const float*)d_in[15];
    const float* bn1b = (const float*)d_in[16];
    const float* tc2w1 = (const float*)d_in[17];
    const float* tc2b1 = (const float*)d_in[18];
    const float* tc2w2 = (const float*)d_in[19];
    const float* tc2b2 = (const float*)d_in[20];
    const float* tc2w3 = (const float*)d_in[21];
    const float* tc2b3 = (const float*)d_in[22];
    const float* bn2g = (const float*)d_in[23];
    const float* bn2b = (const float*)d_in[24];
    const float* fcW = (const float*)d_in[25];
    const float* fcb = (const float*)d_in[26];
    const float* fc4W = (const float*)d_in[27];
    const float* fc4b = (const float*)d_in[28];
    float* out = (float*)d_out;

    char* ws = (char*)d_ws;
    // persistent: x2 (gfeat source) + Ab (FC1 bf16 activations)
    float* x2 = (float*)(ws + 0);                  // 9,961,472 B
    short* Ab = (short*)(ws + 9961472);            // 1,638,400 B
    const size_t ARENA = 9961472 + 1638400;        // 11,599,872

    // arena A (graph phase)
    size_t off = ARENA;
    auto alloc = [&](size_t bytes) -> void* {
        void* p = ws + off;
        off = (off + bytes + 255) & ~(size_t)255;
        return p;
    };
    unsigned* bucket = (unsigned*)alloc((size_t)NN * BCAP * 4);  // 9.96 MB packed
    int* cnt = (int*)alloc((size_t)NN * 4);
    float* dinv = (float*)alloc((size_t)NN * 4);
    unsigned short* Xb = (unsigned short*)alloc((size_t)NN * 32 * 2);  // 2.5 MB
    unsigned short* h1 = (unsigned short*)alloc((size_t)NN * HID * 2); // 5 MB

    // x2t overlaps arena A (bucket region dead after gatherB)
    float* x2t = (float*)(ws + ARENA);             // 9,961,472 B

    // arena C (FC phase) — overlaps arena A and x2t, used only after temporal
    off = ARENA;
    float* part1 = (float*)alloc((size_t)KSPL1 * BATCH * FC1_OUT * 4);
    short* Ab2 = (short*)alloc((size_t)BATCH * FC1_OUT * 2);
    float* part2 = (float*)alloc((size_t)KSPL2 * BATCH * NP2 * 4);
    (void)ws_size; (void)in_sizes; (void)n_in; (void)out_size;

    // ---- bucketed edge build (packed u32 entries) ----
    hipMemsetAsync(cnt, 0, (size_t)NN * 4, stream);
    k_bucket<<<(NE + 255) / 256, 256, 0, stream>>>(ei, ew, cnt, bucket);

    // ---- GCN ----
    k_cvtX<<<NN / 8, 256, 0, stream>>>(data_x, cnt, bucket, Xb, dinv);
    k_gather20<<<NN / 4, 256, 0, stream>>>(cnt, bucket, dinv, Xb, W0, gb0, bn0g,
                                           bn0b, W1, h1);
    k_gatherB<<<NN / 4, 256, 0, stream>>>(cnt, bucket, dinv, h1, gb1, bn1g, bn1b, x2);

    // ---- transpose x2 for coalesced gfeat ----
    k_xpose<<<NN / 64, 256, 0, stream>>>(x2, x2t);

    // ---- temporal (rolling-window, packed fp32) -> bf16 Ab ----
    hipMemsetAsync(Ab, 0, (size_t)BATCH * KP1 * 2, stream);  // zero K-padding
    k_temporal2<<<NN / 16, 256, 0, stream>>>(data_x, x2t, tc1w1, tc1b1, tc1w2, tc1b2,
                                             tc1w3, tc1b3, tc2w1, tc2b1, tc2w2, tc2b2,
                                             tc2w3, tc2b3, bn2g, bn2b, Ab);

    // ---- FC (bf16 MFMA) ----
    {
        dim3 g(FC1_OUT / 64, KSPL1);
        k_gemm1f<<<g, 256, 0, stream>>>(Ab, fcW, part1);
    }
    k_reduce1<<<BATCH * FC1_OUT / 256, 256, 0, stream>>>(part1, fcb, Ab2);
    {
        dim3 g(NP2 / 16, KSPL2);
        k_gemm2f<<<g, 256, 0, stream>>>(Ab2, fc4W, part2);
    }
    k_reduce2<<<(BATCH * NP2 + 255) / 256, 256, 0, stream>>>(part2, fc4b, out);
}

// Round 13
// 179.704 us; speedup vs baseline: 1.2743x; 1.0290x over previous
//
#include <hip/hip_runtime.h>

#define NODES   304
#define BATCH   128
#define TSTEPS  20
#define HID     64
#define GCNIN   20
#define NN      (BATCH*NODES)      // 38912
#define NE      (NN*16)            // 622592
#define SEGSZ   (NN/4)             // 9728 (row-quarter for L2 phasing)
#define BCAP    64                 // bucket capacity per col
#define FC1_IN  (21*NODES)         // 6384
#define KP1     6400               // FC1_IN padded to /32
#define FC1_OUT 2048
#define FC2_OUT 300
#define NP2     304                // FC2_OUT padded to /16
#define BN_EPS  1e-5f

typedef __attribute__((ext_vector_type(8))) short short8;
typedef __attribute__((ext_vector_type(4))) float f32x4;
typedef __attribute__((ext_vector_type(2))) float f32x2;
typedef __attribute__((ext_vector_type(4))) int i32x4;

static __device__ __forceinline__ short f2bf(float x) {
    unsigned u = __float_as_uint(x);
    unsigned r = (u + 0x7FFF + ((u >> 16) & 1)) >> 16;  // RNE
    return (short)r;
}
static __device__ __forceinline__ float bf2f(unsigned short v) {
    return __uint_as_float((unsigned)v << 16);
}

// packed f32->bf16 convert (1 instr for 2 values, RNE); low half = a
static __device__ __forceinline__ int cvtpk(float a, float b) {
    int r;
    asm("v_cvt_pk_bf16_f32 %0, %1, %2" : "=v"(r) : "v"(a), "v"(b));
    return r;
}

static __device__ __forceinline__ float fast_sigmoid(float q) {
    return __builtin_amdgcn_rcpf(1.f + __expf(-q));
}

// packed fp32 FMA (VOP3P)
static __device__ __forceinline__ f32x2 pk_fma(f32x2 a, f32x2 b, f32x2 c) {
    f32x2 d;
    asm("v_pk_fma_f32 %0, %1, %2, %3" : "=v"(d) : "v"(a), "v"(b), "v"(c));
    return d;
}

// DPP row_ror add (VALU pipe, no DS ops)
template <int C>
static __device__ __forceinline__ float dppadd(float v) {
    return v + __int_as_float(
        __builtin_amdgcn_update_dpp(0, __float_as_int(v), C, 0xF, 0xF, false));
}
static __device__ __forceinline__ float rsum16(float v) {
    v = dppadd<0x128>(v);
    v = dppadd<0x124>(v);
    v = dppadd<0x122>(v);
    v = dppadd<0x121>(v);
    return v;
}

// ------- bucketed edge build: ONE global atomic/edge; packed u32 entries -------
// entry = (bf16(weight) << 16) | row16   (row < 38912 < 65536)
__global__ void k_bucket(const int* __restrict__ ei, const float* __restrict__ ew,
                         int* __restrict__ cnt, unsigned* __restrict__ bucket) {
    int e = blockIdx.x * blockDim.x + threadIdx.x;
    if (e < NE) {
        int c = ei[NE + e];
        int slot = atomicAdd(&cnt[c], 1);
        if (slot < BCAP) {
            unsigned v = ((unsigned)(unsigned short)f2bf(ew[e]) << 16) |
                         (unsigned)ei[e];
            bucket[((size_t)c << 6) + slot] = v;
        }
    }
}

// ---- Xb = dinv * data_x as bf16 [NN][32] (64B rows); also computes dinv ----
__global__ __launch_bounds__(256) void k_cvtX(const float* __restrict__ X,
                                              const int* __restrict__ cnt,
                                              const unsigned* __restrict__ bucket,
                                              unsigned short* __restrict__ Xb,
                                              float* __restrict__ dinv) {
    int wv = threadIdx.x >> 5, f = threadIdx.x & 31;  // 8 nodes x 32 lanes
    int n = blockIdx.x * 8 + wv;
    __shared__ float rs[8][2];

    unsigned e0 = bucket[((size_t)n << 6) + f];
    unsigned e1 = bucket[((size_t)n << 6) + 32 + f];
    int deg = cnt[n];
    float xv = (f < GCNIN) ? X[(size_t)n * GCNIN + f] : 0.f;

    int dcap = deg < BCAP ? deg : BCAP;
    float s = ((f < dcap) ? bf2f((unsigned short)(e0 >> 16)) : 0.f) +
              ((32 + f < dcap) ? bf2f((unsigned short)(e1 >> 16)) : 0.f);
    s = rsum16(s);
    if ((f & 15) == 0) rs[wv][f >> 4] = s;
    __syncthreads();

    float dv = rsqrtf(fmaxf(1.f + rs[wv][0] + rs[wv][1], 1e-12f));
    if (f == 0) dinv[n] = dv;
    Xb[(size_t)n * 32 + f] = (f < GCNIN) ? (unsigned short)f2bf(xv * dv)
                                         : (unsigned short)0;
}

// ballot-partition the wave's staged edges by row-quarter (L2 phasing)
static __device__ __forceinline__ void stage_partition(
    int deg, unsigned e, int f, int wv, int (*sIdx)[BCAP], float (*sWt)[BCAP],
    int& dcap) {
    dcap = deg < BCAP ? deg : BCAP;
    bool valid = f < dcap;
    int row = (int)(e & 0xffffu);
    float w = bf2f((unsigned short)(e >> 16));
    int q = (row >= SEGSZ) + (row >= 2 * SEGSZ) + (row >= 3 * SEGSZ);
    unsigned long long b0 = __ballot(valid && q == 0);
    unsigned long long b1 = __ballot(valid && q == 1);
    unsigned long long b2 = __ballot(valid && q == 2);
    unsigned long long b3 = __ballot(valid && q == 3);
    unsigned long long lmask = (1ULL << f) - 1;
    int pos = 0;
    if (q > 0) pos += __popcll(b0);
    if (q > 1) pos += __popcll(b1);
    if (q > 2) pos += __popcll(b2);
    unsigned long long mybal = (q == 0) ? b0 : (q == 1) ? b1 : (q == 2) ? b2 : b3;
    pos += __popcll(mybal & lmask);
    if (valid) {
        sIdx[wv][pos] = row;
        sWt[wv][pos] = w;
    }
}

// ---- layer0: gather RAW 20-dim feats (L2-resident 2.5MB table) + @W0 + BN +
//      ReLU + matvec @W1 -> h1 prescaled bf16 ----
__global__ __launch_bounds__(256) void k_gather20(const int* __restrict__ cnt,
                                                  const unsigned* __restrict__ bucket,
                                                  const float* __restrict__ dinv,
                                                  const unsigned short* __restrict__ Xb,
                                                  const float* __restrict__ W0,
                                                  const float* __restrict__ gb,
                                                  const float* __restrict__ bng,
                                                  const float* __restrict__ bnb,
                                                  const float* __restrict__ W1,
                                                  unsigned short* __restrict__ H1) {
    int wv = threadIdx.x >> 6, f = threadIdx.x & 63;
    int c = blockIdx.x * 4 + wv;
    int g = f >> 4, r = f & 15;  // edge-group, channel-pair lane
    __shared__ int sIdx[4][BCAP];
    __shared__ float sWt[4][BCAP];
    __shared__ float agg[4][32];
    __shared__ float xs[4][HID];

    unsigned be = bucket[((size_t)c << 6) + f];
    int deg = cnt[c];
    float dc = dinv[c];
    unsigned selfv = *(const unsigned*)(Xb + (size_t)c * 32 + 2 * r);

    int dcap;
    stage_partition(deg, be, f, wv, sIdx, sWt, dcap);
    __syncthreads();

    f32x2 acc2;
    acc2[0] = 0.f;
    acc2[1] = 0.f;
    for (int base = 0; base < dcap; base += 16) {
        int idx[4];
        float w[4];
#pragma unroll
        for (int i = 0; i < 4; i++) {
            int l = base + (i << 2) + g;
            int lc = (l < dcap) ? l : dcap - 1;
            idx[i] = sIdx[wv][lc];
            w[i] = (l < dcap) ? sWt[wv][lc] : 0.f;
        }
        unsigned vv[4];
#pragma unroll
        for (int i = 0; i < 4; i++)
            vv[i] = *(const unsigned*)(Xb + (size_t)idx[i] * 32 + 2 * r);
#pragma unroll
        for (int i = 0; i < 4; i++) {
            acc2[0] = fmaf(bf2f((unsigned short)(vv[i] & 0xffff)), w[i], acc2[0]);
            acc2[1] = fmaf(bf2f((unsigned short)(vv[i] >> 16)), w[i], acc2[1]);
        }
    }
    acc2[0] += __shfl_xor(acc2[0], 16);
    acc2[0] += __shfl_xor(acc2[0], 32);
    acc2[1] += __shfl_xor(acc2[1], 16);
    acc2[1] += __shfl_xor(acc2[1], 32);
    if (g == 0) {
        agg[wv][2 * r] = acc2[0] + bf2f((unsigned short)(selfv & 0xffff));
        agg[wv][2 * r + 1] = acc2[1] + bf2f((unsigned short)(selfv >> 16));
    }
    __syncthreads();

    float v = 0.f;
#pragma unroll
    for (int k = 0; k < GCNIN; k++) v = fmaf(agg[wv][k], W0[k * HID + f], v);
    float scale = bng[f] * rsqrtf(1.f + BN_EPS);
    float y = fmaxf(fmaf(v * dc + gb[f], scale, bnb[f]), 0.f);

    xs[wv][f] = y;
    __syncthreads();
    float h = 0.f;
#pragma unroll
    for (int k4 = 0; k4 < HID / 4; k4++) {
        float4 xv = *(const float4*)&xs[wv][k4 * 4];
        h = fmaf(xv.x, W1[(k4 * 4 + 0) * HID + f], h);
        h = fmaf(xv.y, W1[(k4 * 4 + 1) * HID + f], h);
        h = fmaf(xv.z, W1[(k4 * 4 + 2) * HID + f], h);
        h = fmaf(xv.w, W1[(k4 * 4 + 3) * HID + f], h);
    }
    H1[(size_t)c * HID + f] = (unsigned short)f2bf(h * dc);  // pre-scaled
}

// -------- layer1 gather (ushort4 loads, 4 edge-groups) + BN + ReLU -> x2 f32 -----
__global__ __launch_bounds__(256) void k_gatherB(const int* __restrict__ cnt,
                                                 const unsigned* __restrict__ bucket,
                                                 const float* __restrict__ dinv,
                                                 const unsigned short* __restrict__ H,
                                                 const float* __restrict__ gb,
                                                 const float* __restrict__ bng,
                                                 const float* __restrict__ bnb,
                                                 float* __restrict__ XO) {
    int wv = threadIdx.x >> 6, f = threadIdx.x & 63;
    int c = blockIdx.x * 4 + wv;
    int g = f >> 4, r = f & 15;  // edge-group, channel-quad lane
    __shared__ int sIdx[4][BCAP];
    __shared__ float sWt[4][BCAP];

    unsigned be = bucket[((size_t)c << 6) + f];
    int deg = cnt[c];
    float dc = dinv[c];
    ushort4 selfv = *(const ushort4*)(H + (size_t)c * HID + 4 * r);

    int dcap;
    stage_partition(deg, be, f, wv, sIdx, sWt, dcap);
    __syncthreads();

    float a0 = 0.f, a1 = 0.f, a2 = 0.f, a3 = 0.f;
    for (int base = 0; base < dcap; base += 16) {
        int idx[4];
        float w[4];
#pragma unroll
        for (int i = 0; i < 4; i++) {
            int l = base + (i << 2) + g;
            int lc = (l < dcap) ? l : dcap - 1;
            idx[i] = sIdx[wv][lc];
            w[i] = (l < dcap) ? sWt[wv][lc] : 0.f;
        }
        ushort4 hv[4];
#pragma unroll
        for (int i = 0; i < 4; i++)
            hv[i] = *(const ushort4*)(H + (size_t)idx[i] * HID + 4 * r);
#pragma unroll
        for (int i = 0; i < 4; i++) {
            a0 = fmaf(bf2f(hv[i].x), w[i], a0);
            a1 = fmaf(bf2f(hv[i].y), w[i], a1);
            a2 = fmaf(bf2f(hv[i].z), w[i], a2);
            a3 = fmaf(bf2f(hv[i].w), w[i], a3);
        }
    }
    a0 += __shfl_xor(a0, 16); a0 += __shfl_xor(a0, 32);
    a1 += __shfl_xor(a1, 16); a1 += __shfl_xor(a1, 32);
    a2 += __shfl_xor(a2, 16); a2 += __shfl_xor(a2, 32);
    a3 += __shfl_xor(a3, 16); a3 += __shfl_xor(a3, 32);

    if (g == 0) {
        float4 scv = *(const float4*)&bng[4 * r];
        float4 bbv = *(const float4*)&bnb[4 * r];
        float4 gbv = *(const float4*)&gb[4 * r];
        float rr = rsqrtf(1.f + BN_EPS);
        float4 o;
        o.x = fmaxf(fmaf((a0 + bf2f(selfv.x)) * dc + gbv.x, scv.x * rr, bbv.x), 0.f);
        o.y = fmaxf(fmaf((a1 + bf2f(selfv.y)) * dc + gbv.y, scv.y * rr, bbv.y), 0.f);
        o.z = fmaxf(fmaf((a2 + bf2f(selfv.z)) * dc + gbv.z, scv.z * rr, bbv.z), 0.f);
        o.w = fmaxf(fmaf((a3 + bf2f(selfv.w)) * dc + gbv.w, scv.w * rr, bbv.w), 0.f);
        *(float4*)(XO + (size_t)c * HID + 4 * r) = o;
    }
}

// unpack 12 contiguous LDS floats (ch c0..c0+3 × 3 taps) into packed pairs
static __device__ __forceinline__ void load12(const float* base, f32x2 P[2][3]) {
    float4 f0 = *(const float4*)(base);
    float4 f1 = *(const float4*)(base + 4);
    float4 f2 = *(const float4*)(base + 8);
    P[0][0][0] = f0.x; P[0][0][1] = f0.w;
    P[0][1][0] = f0.y; P[0][1][1] = f1.x;
    P[0][2][0] = f0.z; P[0][2][1] = f1.y;
    P[1][0][0] = f1.z; P[1][0][1] = f2.y;
    P[1][1][0] = f1.w; P[1][1][1] = f2.z;
    P[1][2][0] = f2.x; P[1][2][1] = f2.w;
}

// ---------------- fused temporal: packed-fp32, LDS weights, 16 pairs/block ----
// gfeat read DIRECTLY from x2 (4 scalar loads issued at block start; L2/L3-hit)
__global__ __launch_bounds__(256) void k_temporal2(
    const float* __restrict__ data_x, const float* __restrict__ x2,
    const float* __restrict__ w1, const float* __restrict__ b1,
    const float* __restrict__ w2, const float* __restrict__ b2,
    const float* __restrict__ w3, const float* __restrict__ b3,
    const float* __restrict__ v1, const float* __restrict__ vb1,
    const float* __restrict__ v2, const float* __restrict__ vb2,
    const float* __restrict__ v3, const float* __restrict__ vb3,
    const float* __restrict__ bn2g, const float* __restrict__ bn2b,
    short* __restrict__ Ab) {
    int bn0 = blockIdx.x * 16;
    int b = bn0 / NODES, node0 = bn0 % NODES;
    int tid = threadIdx.x;
    int p = tid >> 4;
    int c0 = (tid & 15) << 2;
    int node = node0 + p;

    __shared__ float xs[16][22];
    __shared__ float wlds[1344];

    // gfeat: x2[n2][b>>1] with n2 = (b&1)*19456 + node*64 + c — issue loads NOW,
    // consumed at j==20 (~1300 instrs later; latency fully hidden; L2/L3-hit)
    int n2b = (b & 1) * (NODES * HID) + node * HID + c0;
    int jcol = b >> 1;
    float g0 = x2[(size_t)(n2b + 0) * HID + jcol];
    float g1 = x2[(size_t)(n2b + 1) * HID + jcol];
    float g2 = x2[(size_t)(n2b + 2) * HID + jcol];
    float g3 = x2[(size_t)(n2b + 3) * HID + jcol];

    if (tid < 192) {
        wlds[tid] = w1[tid];
        wlds[192 + tid] = w2[tid];
        wlds[384 + tid] = w3[tid];
        wlds[576 + tid] = v1[tid];
        wlds[768 + tid] = v2[tid];
        wlds[960 + tid] = v3[tid];
    }
    if (tid < 64) {
        wlds[1152 + tid] = b1[tid];
        wlds[1216 + tid] = b2[tid];
        wlds[1280 + tid] = b3[tid];
    }
    for (int i = tid; i < 320; i += 256) {
        int t = i >> 4, pp = i & 15;
        xs[pp][t + 1] = data_x[b * (TSTEPS * NODES) + t * NODES + node0 + pp];
    }
    if (tid < 16) { xs[tid][0] = 0.f; xs[tid][21] = 0.f; }

    float cb1 = vb1[0], cb2 = vb2[0], cb3 = vb3[0];
    float s2 = bn2g[node] * rsqrtf(1.f + BN_EPS);
    float bb2 = bn2b[node];
    short* dst = Ab + (size_t)b * KP1;

    __syncthreads();

    f32x2 A1p[2][3], A2p[2][3], A3p[2][3], B1p[2], B2p[2], B3p[2];
    f32x2 U1p[2][3], U2p[2][3], U3p[2][3];
    load12(&wlds[0 + c0 * 3], A1p);
    load12(&wlds[192 + c0 * 3], A2p);
    load12(&wlds[384 + c0 * 3], A3p);
    load12(&wlds[576 + c0 * 3], U1p);
    load12(&wlds[768 + c0 * 3], U2p);
    load12(&wlds[960 + c0 * 3], U3p);
    {
        float4 t1 = *(const float4*)&wlds[1152 + c0];
        float4 t2 = *(const float4*)&wlds[1216 + c0];
        float4 t3 = *(const float4*)&wlds[1280 + c0];
        B1p[0][0] = t1.x; B1p[0][1] = t1.y; B1p[1][0] = t1.z; B1p[1][1] = t1.w;
        B2p[0][0] = t2.x; B2p[0][1] = t2.y; B2p[1][0] = t2.z; B2p[1][1] = t2.w;
        B3p[0][0] = t3.x; B3p[0][1] = t3.y; B3p[1][0] = t3.z; B3p[1][1] = t3.w;
    }

    f32x2 hA2[2] = {}, hB2[2] = {}, hC2[2];
    float xr0 = xs[p][0], xr1 = xs[p][1];

#pragma unroll
    for (int j = 0; j <= 21; j++) {
        if (j < 20) {
            float xr2 = xs[p][j + 2];
            f32x2 x0d, x1d, x2d;
            x0d[0] = xr0; x0d[1] = xr0;
            x1d[0] = xr1; x1d[1] = xr1;
            x2d[0] = xr2; x2d[1] = xr2;
#pragma unroll
            for (int cp = 0; cp < 2; cp++) {
                f32x2 pv = pk_fma(A1p[cp][2], x2d,
                            pk_fma(A1p[cp][1], x1d, pk_fma(A1p[cp][0], x0d, B1p[cp])));
                f32x2 qv = pk_fma(A2p[cp][2], x2d,
                            pk_fma(A2p[cp][1], x1d, pk_fma(A2p[cp][0], x0d, B2p[cp])));
                f32x2 rv = pk_fma(A3p[cp][2], x2d,
                            pk_fma(A3p[cp][1], x1d, pk_fma(A3p[cp][0], x0d, B3p[cp])));
                hC2[cp][0] = fmaxf(fmaf(pv[0], fast_sigmoid(qv[0]), rv[0]), 0.f);
                hC2[cp][1] = fmaxf(fmaf(pv[1], fast_sigmoid(qv[1]), rv[1]), 0.f);
            }
            xr0 = xr1;
            xr1 = xr2;
        } else if (j == 20) {
            hC2[0][0] = fmaxf(g0, 0.f);
            hC2[0][1] = fmaxf(g1, 0.f);
            hC2[1][0] = fmaxf(g2, 0.f);
            hC2[1][1] = fmaxf(g3, 0.f);
        } else {
            hC2[0][0] = 0.f; hC2[0][1] = 0.f;
            hC2[1][0] = 0.f; hC2[1][1] = 0.f;
        }
        if (j >= 1) {
            int w = j - 1;
            f32x2 pa, qa, ra;
            pa[0] = 0.f; pa[1] = 0.f;
            qa[0] = 0.f; qa[1] = 0.f;
            ra[0] = 0.f; ra[1] = 0.f;
#pragma unroll
            for (int cp = 0; cp < 2; cp++) {
                pa = pk_fma(U1p[cp][0], hA2[cp], pa);
                pa = pk_fma(U1p[cp][1], hB2[cp], pa);
                pa = pk_fma(U1p[cp][2], hC2[cp], pa);
                qa = pk_fma(U2p[cp][0], hA2[cp], qa);
                qa = pk_fma(U2p[cp][1], hB2[cp], qa);
                qa = pk_fma(U2p[cp][2], hC2[cp], qa);
                ra = pk_fma(U3p[cp][0], hA2[cp], ra);
                ra = pk_fma(U3p[cp][1], hB2[cp], ra);
                ra = pk_fma(U3p[cp][2], hC2[cp], ra);
            }
            float pp_ = rsum16(pa[0] + pa[1]);
            float qq_ = rsum16(qa[0] + qa[1]);
            float rr_ = rsum16(ra[0] + ra[1]);
            float P = pp_ + cb1, Q = qq_ + cb2, R = rr_ + cb3;
            float hv = fmaxf(fmaf(P, fast_sigmoid(Q), R), 0.f);
            if ((tid & 15) == 0) dst[w * NODES + node] = f2bf(fmaf(hv, s2, bb2));
        }
        hA2[0] = hB2[0]; hA2[1] = hB2[1];
        hB2[0] = hC2[0]; hB2[1] = hC2[1];
    }
}

// ---------------- FC1 MFMA GEMM, B read directly from f32 fcW ----------------
#define KSPL1 8
#define KCH1  (KP1 / KSPL1)  // 800
__global__ __launch_bounds__(256) void k_gemm1f(const short* __restrict__ Ab,
                                                const float* __restrict__ fcW,
                                                float* __restrict__ part) {
    int lane = threadIdx.x & 63, wv = threadIdx.x >> 6;
    int r = lane & 15, kg = lane >> 4;
    int nb = blockIdx.x * 64, sp = blockIdx.y;

    f32x4 acc[2][4] = {};
    const short* a0 = Ab + (size_t)(wv * 32 + r) * KP1;
    const short* a1 = a0 + (size_t)16 * KP1;

    int k0 = sp * KCH1 + kg * 8;
    const float* wp = fcW + (size_t)k0 * FC1_OUT + nb + r;
    bool tailblk = (sp == KSPL1 - 1);

#pragma unroll 1
    for (int s = 0; s < KCH1 / 32; s++, k0 += 32) {
        short8 av0 = *(const short8*)(a0 + k0);
        short8 av1 = *(const short8*)(a1 + k0);
        short8 bv[4];
        if (tailblk && s == KCH1 / 32 - 1) {
#pragma unroll
            for (int f = 0; f < 4; f++) {
                float wf[8];
#pragma unroll
                for (int i = 0; i < 8; i++)
                    wf[i] = (k0 + i < FC1_IN) ? wp[(size_t)i * FC1_OUT + f * 16] : 0.f;
                i32x4 pk;
                pk[0] = cvtpk(wf[0], wf[1]);
                pk[1] = cvtpk(wf[2], wf[3]);
                pk[2] = cvtpk(wf[4], wf[5]);
                pk[3] = cvtpk(wf[6], wf[7]);
                bv[f] = __builtin_bit_cast(short8, pk);
            }
        } else {
#pragma unroll
            for (int f = 0; f < 4; f++) {
                float wf[8];
#pragma unroll
                for (int i = 0; i < 8; i++)
                    wf[i] = wp[(size_t)i * FC1_OUT + f * 16];
                i32x4 pk;
                pk[0] = cvtpk(wf[0], wf[1]);
                pk[1] = cvtpk(wf[2], wf[3]);
                pk[2] = cvtpk(wf[4], wf[5]);
                pk[3] = cvtpk(wf[6], wf[7]);
                bv[f] = __builtin_bit_cast(short8, pk);
            }
        }
        acc[0][0] = __builtin_amdgcn_mfma_f32_16x16x32_bf16(av0, bv[0], acc[0][0], 0, 0, 0);
        acc[1][0] = __builtin_amdgcn_mfma_f32_16x16x32_bf16(av1, bv[0], acc[1][0], 0, 0, 0);
        acc[0][1] = __builtin_amdgcn_mfma_f32_16x16x32_bf16(av0, bv[1], acc[0][1], 0, 0, 0);
        acc[1][1] = __builtin_amdgcn_mfma_f32_16x16x32_bf16(av1, bv[1], acc[1][1], 0, 0, 0);
        acc[0][2] = __builtin_amdgcn_mfma_f32_16x16x32_bf16(av0, bv[2], acc[0][2], 0, 0, 0);
        acc[1][2] = __builtin_amdgcn_mfma_f32_16x16x32_bf16(av1, bv[2], acc[1][2], 0, 0, 0);
        acc[0][3] = __builtin_amdgcn_mfma_f32_16x16x32_bf16(av0, bv[3], acc[0][3], 0, 0, 0);
        acc[1][3] = __builtin_amdgcn_mfma_f32_16x16x32_bf16(av1, bv[3], acc[1][3], 0, 0, 0);
        wp += (size_t)32 * FC1_OUT;
    }

    float* dst = part + (size_t)sp * BATCH * FC1_OUT;
#pragma unroll
    for (int m = 0; m < 2; m++)
#pragma unroll
        for (int f = 0; f < 4; f++)
#pragma unroll
            for (int j = 0; j < 4; j++) {
                int row = wv * 32 + m * 16 + kg * 4 + j;
                int col = nb + f * 16 + r;
                dst[(size_t)row * FC1_OUT + col] = acc[m][f][j];
            }
}

// reduce split-K + bias + ReLU -> bf16 activations for FC2
__global__ __launch_bounds__(256) void k_reduce1(const float* __restrict__ part,
                                                 const float* __restrict__ bias,
                                                 short* __restrict__ Ab2) {
    int idx = blockIdx.x * 256 + threadIdx.x;
    int o = idx & (FC1_OUT - 1);
    float s = bias[o];
#pragma unroll
    for (int sp = 0; sp < KSPL1; sp++) s += part[(size_t)sp * BATCH * FC1_OUT + idx];
    Ab2[idx] = f2bf(fmaxf(s, 0.f));
}

// ---------------- FC2 MFMA GEMM, B read directly from f32 fc4W ----------------
#define KSPL2 8
#define KCH2  (FC1_OUT / KSPL2)  // 256
__global__ __launch_bounds__(256) void k_gemm2f(const short* __restrict__ Ab,
                                                const float* __restrict__ fc4W,
                                                float* __restrict__ part) {
    int lane = threadIdx.x & 63, wv = threadIdx.x >> 6;
    int r = lane & 15, kg = lane >> 4;
    int nb = blockIdx.x * 16, sp = blockIdx.y;

    f32x4 acc[2] = {};
    const short* a0 = Ab + (size_t)(wv * 32 + r) * FC1_OUT;
    const short* a1 = a0 + (size_t)16 * FC1_OUT;
    int col = nb + r;
    int colc = (col < FC2_OUT) ? col : FC2_OUT - 1;  // clamp; pad cols never read

    int k0 = sp * KCH2 + kg * 8;
    const float* wp = fc4W + (size_t)k0 * FC2_OUT + colc;
#pragma unroll 1
    for (int s = 0; s < KCH2 / 32; s++, k0 += 32) {
        short8 av0 = *(const short8*)(a0 + k0);
        short8 av1 = *(const short8*)(a1 + k0);
        float wf[8];
#pragma unroll
        for (int i = 0; i < 8; i++) wf[i] = wp[(size_t)i * FC2_OUT];
        i32x4 pk;
        pk[0] = cvtpk(wf[0], wf[1]);
        pk[1] = cvtpk(wf[2], wf[3]);
        pk[2] = cvtpk(wf[4], wf[5]);
        pk[3] = cvtpk(wf[6], wf[7]);
        short8 bv = __builtin_bit_cast(short8, pk);
        acc[0] = __builtin_amdgcn_mfma_f32_16x16x32_bf16(av0, bv, acc[0], 0, 0, 0);
        acc[1] = __builtin_amdgcn_mfma_f32_16x16x32_bf16(av1, bv, acc[1], 0, 0, 0);
        wp += (size_t)32 * FC2_OUT;
    }

    float* dst = part + (size_t)sp * BATCH * NP2;
#pragma unroll
    for (int m = 0; m < 2; m++)
#pragma unroll
        for (int j = 0; j < 4; j++) {
            int row = wv * 32 + m * 16 + kg * 4 + j;
            dst[(size_t)row * NP2 + col] = acc[m][j];
        }
}

__global__ __launch_bounds__(256) void k_reduce2(const float* __restrict__ part,
                                                 const float* __restrict__ bias,
                                                 float* __restrict__ out) {
    int idx = blockIdx.x * 256 + threadIdx.x;
    if (idx >= BATCH * NP2) return;
    int b = idx / NP2, o = idx % NP2;
    float s = 0.f;
#pragma unroll
    for (int sp = 0; sp < KSPL2; sp++) s += part[(size_t)sp * BATCH * NP2 + idx];
    if (o < FC2_OUT) out[(size_t)b * FC2_OUT + o] = s + bias[o];
}

extern "C" void kernel_launch(void* const* d_in, const int* in_sizes, int n_in,
                              void* d_out, int out_size, void* d_ws, size_t ws_size,
                              hipStream_t stream) {
    const float* data_x = (const float*)d_in[0];
    const int* ei = (const int*)d_in[1];
    const float* ew = (const float*)d_in[2];
    const float* tc1w1 = (const float*)d_in[3];
    const float* tc1b1 = (const float*)d_in[4];
    const float* tc1w2 = (const float*)d_in[5];
    const float* tc1b2 = (const float*)d_in[6];
    const float* tc1w3 = (const float*)d_in[7];
    const float* tc1b3 = (const float*)d_in[8];
    const float* W0 = (const float*)d_in[9];
    const float* gb0 = (const float*)d_in[10];
    const float* bn0g = (const float*)d_in[11];
    const float* bn0b = (const float*)d_in[12];
    const float* W1 = (const float*)d_in[13];
    const float* gb1 = (const float*)d_in[14];
    const float* bn1g = (const float*)d_in[15];
    const float* bn1b = (const float*)d_in[16];
    const float* tc2w1 = (const float*)d_in[17];
    const float* tc2b1 = (const float*)d_in[18];
    const float* tc2w2 = (const float*)d_in[19];
    const float* tc2b2 = (const float*)d_in[20];
    const float* tc2w3 = (const float*)d_in[21];
    const float* tc2b3 = (const float*)d_in[22];
    const float* bn2g = (const float*)d_in[23];
    const float* bn2b = (const float*)d_in[24];
    const float* fcW = (const float*)d_in[25];
    const float* fcb = (const float*)d_in[26];
    const float* fc4W = (const float*)d_in[27];
    const float* fc4b = (const float*)d_in[28];
    float* out = (float*)d_out;

    char* ws = (char*)d_ws;
    // persistent: x2 (gfeat source) + Ab (FC1 bf16 activations)
    float* x2 = (float*)(ws + 0);                  // 9,961,472 B
    short* Ab = (short*)(ws + 9961472);            // 1,638,400 B
    const size_t ARENA = 9961472 + 1638400;        // 11,599,872

    // arena A (graph phase)
    size_t off = ARENA;
    auto alloc = [&](size_t bytes) -> void* {
        void* p = ws + off;
        off = (off + bytes + 255) & ~(size_t)255;
        return p;
    };
    unsigned* bucket = (unsigned*)alloc((size_t)NN * BCAP * 4);  // 9.96 MB packed
    int* cnt = (int*)alloc((size_t)NN * 4);
    float* dinv = (float*)alloc((size_t)NN * 4);
    unsigned short* Xb = (unsigned short*)alloc((size_t)NN * 32 * 2);  // 2.5 MB
    unsigned short* h1 = (unsigned short*)alloc((size_t)NN * HID * 2); // 5 MB

    // arena C (FC phase) — overlaps arena A, used only after temporal
    off = ARENA;
    float* part1 = (float*)alloc((size_t)KSPL1 * BATCH * FC1_OUT * 4);
    short* Ab2 = (short*)alloc((size_t)BATCH * FC1_OUT * 2);
    float* part2 = (float*)alloc((size_t)KSPL2 * BATCH * NP2 * 4);
    (void)ws_size; (void)in_sizes; (void)n_in; (void)out_size;

    // ---- bucketed edge build (packed u32 entries) ----
    hipMemsetAsync(cnt, 0, (size_t)NN * 4, stream);
    k_bucket<<<(NE + 255) / 256, 256, 0, stream>>>(ei, ew, cnt, bucket);

    // ---- GCN ----
    k_cvtX<<<NN / 8, 256, 0, stream>>>(data_x, cnt, bucket, Xb, dinv);
    k_gather20<<<NN / 4, 256, 0, stream>>>(cnt, bucket, dinv, Xb, W0, gb0, bn0g,
                                           bn0b, W1, h1);
    k_gatherB<<<NN / 4, 256, 0, stream>>>(cnt, bucket, dinv, h1, gb1, bn1g, bn1b, x2);

    // ---- temporal (rolling-window, packed fp32; gfeat direct from x2) ----
    hipMemsetAsync(Ab, 0, (size_t)BATCH * KP1 * 2, stream);  // zero K-padding
    k_temporal2<<<NN / 16, 256, 0, stream>>>(data_x, x2, tc1w1, tc1b1, tc1w2, tc1b2,
                                             tc1w3, tc1b3, tc2w1, tc2b1, tc2w2, tc2b2,
                                             tc2w3, tc2b3, bn2g, bn2b, Ab);

    // ---- FC (bf16 MFMA, packed-convert B) ----
    {
        dim3 g(FC1_OUT / 64, KSPL1);
        k_gemm1f<<<g, 256, 0, stream>>>(Ab, fcW, part1);
    }
    k_reduce1<<<BATCH * FC1_OUT / 256, 256, 0, stream>>>(part1, fcb, Ab2);
    {
        dim3 g(NP2 / 16, KSPL2);
        k_gemm2f<<<g, 256, 0, stream>>>(Ab2, fc4W, part2);
    }
    k_reduce2<<<(BATCH * NP2 + 255) / 256, 256, 0, stream>>>(part2, fc4b, out);
}

// Round 14
// 179.205 us; speedup vs baseline: 1.2778x; 1.0028x over previous
//
#include <hip/hip_runtime.h>

#define NODES   304
#define BATCH   128
#define TSTEPS  20
#define HID     64
#define GCNIN   20
#define NN      (BATCH*NODES)      // 38912
#define NE      (NN*16)            // 622592
#define SEGSZ   (NN/4)             // 9728 (row-quarter for L2 phasing)
#define BCAP    64                 // bucket capacity per col
#define FC1_IN  (21*NODES)         // 6384
#define KP1     6400               // FC1_IN padded to /32
#define FC1_OUT 2048
#define FC2_OUT 300
#define NP2     304                // FC2_OUT padded to /16
#define BN_EPS  1e-5f

typedef __attribute__((ext_vector_type(8))) short short8;
typedef __attribute__((ext_vector_type(4))) float f32x4;
typedef __attribute__((ext_vector_type(2))) float f32x2;
typedef __attribute__((ext_vector_type(4))) int i32x4;

static __device__ __forceinline__ short f2bf(float x) {
    unsigned u = __float_as_uint(x);
    unsigned r = (u + 0x7FFF + ((u >> 16) & 1)) >> 16;  // RNE
    return (short)r;
}
static __device__ __forceinline__ float bf2f(unsigned short v) {
    return __uint_as_float((unsigned)v << 16);
}

// packed f32->bf16 convert (1 instr for 2 values, RNE); low half = a
static __device__ __forceinline__ int cvtpk(float a, float b) {
    int r;
    asm("v_cvt_pk_bf16_f32 %0, %1, %2" : "=v"(r) : "v"(a), "v"(b));
    return r;
}

static __device__ __forceinline__ float fast_sigmoid(float q) {
    return __builtin_amdgcn_rcpf(1.f + __expf(-q));
}

// packed fp32 FMA (VOP3P)
static __device__ __forceinline__ f32x2 pk_fma(f32x2 a, f32x2 b, f32x2 c) {
    f32x2 d;
    asm("v_pk_fma_f32 %0, %1, %2, %3" : "=v"(d) : "v"(a), "v"(b), "v"(c));
    return d;
}

// DPP row_ror add (VALU pipe, no DS ops)
template <int C>
static __device__ __forceinline__ float dppadd(float v) {
    return v + __int_as_float(
        __builtin_amdgcn_update_dpp(0, __float_as_int(v), C, 0xF, 0xF, false));
}
static __device__ __forceinline__ float rsum16(float v) {
    v = dppadd<0x128>(v);
    v = dppadd<0x124>(v);
    v = dppadd<0x122>(v);
    v = dppadd<0x121>(v);
    return v;
}

// ------- bucketed edge build: ONE global atomic/edge; packed u32 entries -------
// entry = (bf16(weight) << 16) | row16   (row < 38912 < 65536)
__global__ void k_bucket(const int* __restrict__ ei, const float* __restrict__ ew,
                         int* __restrict__ cnt, unsigned* __restrict__ bucket) {
    int e = blockIdx.x * blockDim.x + threadIdx.x;
    if (e < NE) {
        int c = ei[NE + e];
        int slot = atomicAdd(&cnt[c], 1);
        if (slot < BCAP) {
            unsigned v = ((unsigned)(unsigned short)f2bf(ew[e]) << 16) |
                         (unsigned)ei[e];
            bucket[((size_t)c << 6) + slot] = v;
        }
    }
}

// ---- Xb = dinv * data_x as bf16 [NN][32] (64B rows); also computes dinv ----
__global__ __launch_bounds__(256) void k_cvtX(const float* __restrict__ X,
                                              const int* __restrict__ cnt,
                                              const unsigned* __restrict__ bucket,
                                              unsigned short* __restrict__ Xb,
                                              float* __restrict__ dinv) {
    int wv = threadIdx.x >> 5, f = threadIdx.x & 31;  // 8 nodes x 32 lanes
    int n = blockIdx.x * 8 + wv;
    __shared__ float rs[8][2];

    unsigned e0 = bucket[((size_t)n << 6) + f];
    unsigned e1 = bucket[((size_t)n << 6) + 32 + f];
    int deg = cnt[n];
    float xv = (f < GCNIN) ? X[(size_t)n * GCNIN + f] : 0.f;

    int dcap = deg < BCAP ? deg : BCAP;
    float s = ((f < dcap) ? bf2f((unsigned short)(e0 >> 16)) : 0.f) +
              ((32 + f < dcap) ? bf2f((unsigned short)(e1 >> 16)) : 0.f);
    s = rsum16(s);
    if ((f & 15) == 0) rs[wv][f >> 4] = s;
    __syncthreads();

    float dv = rsqrtf(fmaxf(1.f + rs[wv][0] + rs[wv][1], 1e-12f));
    if (f == 0) dinv[n] = dv;
    Xb[(size_t)n * 32 + f] = (f < GCNIN) ? (unsigned short)f2bf(xv * dv)
                                         : (unsigned short)0;
}

// ballot-partition the wave's staged edges by row-quarter (L2 phasing)
static __device__ __forceinline__ void stage_partition(
    int deg, unsigned e, int f, int wv, int (*sIdx)[BCAP], float (*sWt)[BCAP],
    int& dcap) {
    dcap = deg < BCAP ? deg : BCAP;
    bool valid = f < dcap;
    int row = (int)(e & 0xffffu);
    float w = bf2f((unsigned short)(e >> 16));
    int q = (row >= SEGSZ) + (row >= 2 * SEGSZ) + (row >= 3 * SEGSZ);
    unsigned long long b0 = __ballot(valid && q == 0);
    unsigned long long b1 = __ballot(valid && q == 1);
    unsigned long long b2 = __ballot(valid && q == 2);
    unsigned long long b3 = __ballot(valid && q == 3);
    unsigned long long lmask = (1ULL << f) - 1;
    int pos = 0;
    if (q > 0) pos += __popcll(b0);
    if (q > 1) pos += __popcll(b1);
    if (q > 2) pos += __popcll(b2);
    unsigned long long mybal = (q == 0) ? b0 : (q == 1) ? b1 : (q == 2) ? b2 : b3;
    pos += __popcll(mybal & lmask);
    if (valid) {
        sIdx[wv][pos] = row;
        sWt[wv][pos] = w;
    }
}

// ---- layer0: gather RAW 20-dim feats (L2-resident 2.5MB table) + @W0 + BN +
//      ReLU + matvec @W1 -> h1 prescaled bf16 ----
__global__ __launch_bounds__(256) void k_gather20(const int* __restrict__ cnt,
                                                  const unsigned* __restrict__ bucket,
                                                  const float* __restrict__ dinv,
                                                  const unsigned short* __restrict__ Xb,
                                                  const float* __restrict__ W0,
                                                  const float* __restrict__ gb,
                                                  const float* __restrict__ bng,
                                                  const float* __restrict__ bnb,
                                                  const float* __restrict__ W1,
                                                  unsigned short* __restrict__ H1) {
    int wv = threadIdx.x >> 6, f = threadIdx.x & 63;
    int c = blockIdx.x * 4 + wv;
    int g = f >> 4, r = f & 15;  // edge-group, channel-pair lane
    __shared__ int sIdx[4][BCAP];
    __shared__ float sWt[4][BCAP];
    __shared__ float agg[4][32];
    __shared__ float xs[4][HID];

    unsigned be = bucket[((size_t)c << 6) + f];
    int deg = cnt[c];
    float dc = dinv[c];
    unsigned selfv = *(const unsigned*)(Xb + (size_t)c * 32 + 2 * r);

    int dcap;
    stage_partition(deg, be, f, wv, sIdx, sWt, dcap);
    __syncthreads();

    f32x2 acc2;
    acc2[0] = 0.f;
    acc2[1] = 0.f;
    for (int base = 0; base < dcap; base += 16) {
        int idx[4];
        float w[4];
#pragma unroll
        for (int i = 0; i < 4; i++) {
            int l = base + (i << 2) + g;
            int lc = (l < dcap) ? l : dcap - 1;
            idx[i] = sIdx[wv][lc];
            w[i] = (l < dcap) ? sWt[wv][lc] : 0.f;
        }
        unsigned vv[4];
#pragma unroll
        for (int i = 0; i < 4; i++)
            vv[i] = *(const unsigned*)(Xb + (size_t)idx[i] * 32 + 2 * r);
#pragma unroll
        for (int i = 0; i < 4; i++) {
            acc2[0] = fmaf(bf2f((unsigned short)(vv[i] & 0xffff)), w[i], acc2[0]);
            acc2[1] = fmaf(bf2f((unsigned short)(vv[i] >> 16)), w[i], acc2[1]);
        }
    }
    acc2[0] += __shfl_xor(acc2[0], 16);
    acc2[0] += __shfl_xor(acc2[0], 32);
    acc2[1] += __shfl_xor(acc2[1], 16);
    acc2[1] += __shfl_xor(acc2[1], 32);
    if (g == 0) {
        agg[wv][2 * r] = acc2[0] + bf2f((unsigned short)(selfv & 0xffff));
        agg[wv][2 * r + 1] = acc2[1] + bf2f((unsigned short)(selfv >> 16));
    }
    __syncthreads();

    float v = 0.f;
#pragma unroll
    for (int k = 0; k < GCNIN; k++) v = fmaf(agg[wv][k], W0[k * HID + f], v);
    float scale = bng[f] * rsqrtf(1.f + BN_EPS);
    float y = fmaxf(fmaf(v * dc + gb[f], scale, bnb[f]), 0.f);

    xs[wv][f] = y;
    __syncthreads();
    float h = 0.f;
#pragma unroll
    for (int k4 = 0; k4 < HID / 4; k4++) {
        float4 xv = *(const float4*)&xs[wv][k4 * 4];
        h = fmaf(xv.x, W1[(k4 * 4 + 0) * HID + f], h);
        h = fmaf(xv.y, W1[(k4 * 4 + 1) * HID + f], h);
        h = fmaf(xv.z, W1[(k4 * 4 + 2) * HID + f], h);
        h = fmaf(xv.w, W1[(k4 * 4 + 3) * HID + f], h);
    }
    H1[(size_t)c * HID + f] = (unsigned short)f2bf(h * dc);  // pre-scaled
}

// -------- layer1 gather (ushort4 loads, 4 edge-groups) + BN + ReLU -> x2 f32 -----
__global__ __launch_bounds__(256) void k_gatherB(const int* __restrict__ cnt,
                                                 const unsigned* __restrict__ bucket,
                                                 const float* __restrict__ dinv,
                                                 const unsigned short* __restrict__ H,
                                                 const float* __restrict__ gb,
                                                 const float* __restrict__ bng,
                                                 const float* __restrict__ bnb,
                                                 float* __restrict__ XO) {
    int wv = threadIdx.x >> 6, f = threadIdx.x & 63;
    int c = blockIdx.x * 4 + wv;
    int g = f >> 4, r = f & 15;  // edge-group, channel-quad lane
    __shared__ int sIdx[4][BCAP];
    __shared__ float sWt[4][BCAP];

    unsigned be = bucket[((size_t)c << 6) + f];
    int deg = cnt[c];
    float dc = dinv[c];
    ushort4 selfv = *(const ushort4*)(H + (size_t)c * HID + 4 * r);

    int dcap;
    stage_partition(deg, be, f, wv, sIdx, sWt, dcap);
    __syncthreads();

    float a0 = 0.f, a1 = 0.f, a2 = 0.f, a3 = 0.f;
    for (int base = 0; base < dcap; base += 16) {
        int idx[4];
        float w[4];
#pragma unroll
        for (int i = 0; i < 4; i++) {
            int l = base + (i << 2) + g;
            int lc = (l < dcap) ? l : dcap - 1;
            idx[i] = sIdx[wv][lc];
            w[i] = (l < dcap) ? sWt[wv][lc] : 0.f;
        }
        ushort4 hv[4];
#pragma unroll
        for (int i = 0; i < 4; i++)
            hv[i] = *(const ushort4*)(H + (size_t)idx[i] * HID + 4 * r);
#pragma unroll
        for (int i = 0; i < 4; i++) {
            a0 = fmaf(bf2f(hv[i].x), w[i], a0);
            a1 = fmaf(bf2f(hv[i].y), w[i], a1);
            a2 = fmaf(bf2f(hv[i].z), w[i], a2);
            a3 = fmaf(bf2f(hv[i].w), w[i], a3);
        }
    }
    a0 += __shfl_xor(a0, 16); a0 += __shfl_xor(a0, 32);
    a1 += __shfl_xor(a1, 16); a1 += __shfl_xor(a1, 32);
    a2 += __shfl_xor(a2, 16); a2 += __shfl_xor(a2, 32);
    a3 += __shfl_xor(a3, 16); a3 += __shfl_xor(a3, 32);

    if (g == 0) {
        float4 scv = *(const float4*)&bng[4 * r];
        float4 bbv = *(const float4*)&bnb[4 * r];
        float4 gbv = *(const float4*)&gb[4 * r];
        float rr = rsqrtf(1.f + BN_EPS);
        float4 o;
        o.x = fmaxf(fmaf((a0 + bf2f(selfv.x)) * dc + gbv.x, scv.x * rr, bbv.x), 0.f);
        o.y = fmaxf(fmaf((a1 + bf2f(selfv.y)) * dc + gbv.y, scv.y * rr, bbv.y), 0.f);
        o.z = fmaxf(fmaf((a2 + bf2f(selfv.z)) * dc + gbv.z, scv.z * rr, bbv.z), 0.f);
        o.w = fmaxf(fmaf((a3 + bf2f(selfv.w)) * dc + gbv.w, scv.w * rr, bbv.w), 0.f);
        *(float4*)(XO + (size_t)c * HID + 4 * r) = o;
    }
}

// ---------------- x2 [38912][64] -> x2t [64][38912] ----------------
__global__ __launch_bounds__(256) void k_xpose(const float* __restrict__ x2,
                                               float* __restrict__ x2t) {
    __shared__ float tile[64][65];
    int n0 = blockIdx.x * 64;
    for (int i = threadIdx.x; i < 4096; i += 256) {
        int r = i >> 6, h = i & 63;
        tile[r][h] = x2[(size_t)(n0 + r) * 64 + h];
    }
    __syncthreads();
    for (int i = threadIdx.x; i < 4096; i += 256) {
        int h = i >> 6, c = i & 63;
        x2t[(size_t)h * NN + n0 + c] = tile[c][h];
    }
}

// unpack 12 contiguous LDS floats (ch c0..c0+3 × 3 taps) into packed pairs
static __device__ __forceinline__ void load12(const float* base, f32x2 P[2][3]) {
    float4 f0 = *(const float4*)(base);
    float4 f1 = *(const float4*)(base + 4);
    float4 f2 = *(const float4*)(base + 8);
    P[0][0][0] = f0.x; P[0][0][1] = f0.w;
    P[0][1][0] = f0.y; P[0][1][1] = f1.x;
    P[0][2][0] = f0.z; P[0][2][1] = f1.y;
    P[1][0][0] = f1.z; P[1][0][1] = f2.y;
    P[1][1][0] = f1.w; P[1][1][1] = f2.z;
    P[1][2][0] = f2.x; P[1][2][1] = f2.w;
}

// ---------------- fused temporal: packed-fp32, LDS weights, 16 pairs/block ----
// (gfeat via coalesced float4 from x2t — measured-best R12 form)
__global__ __launch_bounds__(256) void k_temporal2(
    const float* __restrict__ data_x, const float* __restrict__ x2t,
    const float* __restrict__ w1, const float* __restrict__ b1,
    const float* __restrict__ w2, const float* __restrict__ b2,
    const float* __restrict__ w3, const float* __restrict__ b3,
    const float* __restrict__ v1, const float* __restrict__ vb1,
    const float* __restrict__ v2, const float* __restrict__ vb2,
    const float* __restrict__ v3, const float* __restrict__ vb3,
    const float* __restrict__ bn2g, const float* __restrict__ bn2b,
    short* __restrict__ Ab) {
    int bn0 = blockIdx.x * 16;
    int b = bn0 / NODES, node0 = bn0 % NODES;
    int tid = threadIdx.x;
    int p = tid >> 4;
    int c0 = (tid & 15) << 2;
    int node = node0 + p;

    __shared__ float xs[16][22];
    __shared__ float wlds[1344];

    if (tid < 192) {
        wlds[tid] = w1[tid];
        wlds[192 + tid] = w2[tid];
        wlds[384 + tid] = w3[tid];
        wlds[576 + tid] = v1[tid];
        wlds[768 + tid] = v2[tid];
        wlds[960 + tid] = v3[tid];
    }
    if (tid < 64) {
        wlds[1152 + tid] = b1[tid];
        wlds[1216 + tid] = b2[tid];
        wlds[1280 + tid] = b3[tid];
    }
    for (int i = tid; i < 320; i += 256) {
        int t = i >> 4, pp = i & 15;
        xs[pp][t + 1] = data_x[b * (TSTEPS * NODES) + t * NODES + node0 + pp];
    }
    if (tid < 16) { xs[tid][0] = 0.f; xs[tid][21] = 0.f; }

    float cb1 = vb1[0], cb2 = vb2[0], cb3 = vb3[0];
    float s2 = bn2g[node] * rsqrtf(1.f + BN_EPS);
    float bb2 = bn2b[node];
    short* dst = Ab + (size_t)b * KP1;

    __syncthreads();

    f32x2 A1p[2][3], A2p[2][3], A3p[2][3], B1p[2], B2p[2], B3p[2];
    f32x2 U1p[2][3], U2p[2][3], U3p[2][3];
    load12(&wlds[0 + c0 * 3], A1p);
    load12(&wlds[192 + c0 * 3], A2p);
    load12(&wlds[384 + c0 * 3], A3p);
    load12(&wlds[576 + c0 * 3], U1p);
    load12(&wlds[768 + c0 * 3], U2p);
    load12(&wlds[960 + c0 * 3], U3p);
    {
        float4 t1 = *(const float4*)&wlds[1152 + c0];
        float4 t2 = *(const float4*)&wlds[1216 + c0];
        float4 t3 = *(const float4*)&wlds[1280 + c0];
        B1p[0][0] = t1.x; B1p[0][1] = t1.y; B1p[1][0] = t1.z; B1p[1][1] = t1.w;
        B2p[0][0] = t2.x; B2p[0][1] = t2.y; B2p[1][0] = t2.z; B2p[1][1] = t2.w;
        B3p[0][0] = t3.x; B3p[0][1] = t3.y; B3p[1][0] = t3.z; B3p[1][1] = t3.w;
    }

    f32x2 hA2[2] = {}, hB2[2] = {}, hC2[2];
    float xr0 = xs[p][0], xr1 = xs[p][1];

#pragma unroll
    for (int j = 0; j <= 21; j++) {
        if (j < 20) {
            float xr2 = xs[p][j + 2];
            f32x2 x0d, x1d, x2d;
            x0d[0] = xr0; x0d[1] = xr0;
            x1d[0] = xr1; x1d[1] = xr1;
            x2d[0] = xr2; x2d[1] = xr2;
#pragma unroll
            for (int cp = 0; cp < 2; cp++) {
                f32x2 pv = pk_fma(A1p[cp][2], x2d,
                            pk_fma(A1p[cp][1], x1d, pk_fma(A1p[cp][0], x0d, B1p[cp])));
                f32x2 qv = pk_fma(A2p[cp][2], x2d,
                            pk_fma(A2p[cp][1], x1d, pk_fma(A2p[cp][0], x0d, B2p[cp])));
                f32x2 rv = pk_fma(A3p[cp][2], x2d,
                            pk_fma(A3p[cp][1], x1d, pk_fma(A3p[cp][0], x0d, B3p[cp])));
                hC2[cp][0] = fmaxf(fmaf(pv[0], fast_sigmoid(qv[0]), rv[0]), 0.f);
                hC2[cp][1] = fmaxf(fmaf(pv[1], fast_sigmoid(qv[1]), rv[1]), 0.f);
            }
            xr0 = xr1;
            xr1 = xr2;
        } else if (j == 20) {
            const float4 gv = *(const float4*)(x2t + (size_t)(b >> 1) * NN +
                                               (b & 1) * (NODES * HID) + node * HID + c0);
            hC2[0][0] = fmaxf(gv.x, 0.f);
            hC2[0][1] = fmaxf(gv.y, 0.f);
            hC2[1][0] = fmaxf(gv.z, 0.f);
            hC2[1][1] = fmaxf(gv.w, 0.f);
        } else {
            hC2[0][0] = 0.f; hC2[0][1] = 0.f;
            hC2[1][0] = 0.f; hC2[1][1] = 0.f;
        }
        if (j >= 1) {
            int w = j - 1;
            f32x2 pa, qa, ra;
            pa[0] = 0.f; pa[1] = 0.f;
            qa[0] = 0.f; qa[1] = 0.f;
            ra[0] = 0.f; ra[1] = 0.f;
#pragma unroll
            for (int cp = 0; cp < 2; cp++) {
                pa = pk_fma(U1p[cp][0], hA2[cp], pa);
                pa = pk_fma(U1p[cp][1], hB2[cp], pa);
                pa = pk_fma(U1p[cp][2], hC2[cp], pa);
                qa = pk_fma(U2p[cp][0], hA2[cp], qa);
                qa = pk_fma(U2p[cp][1], hB2[cp], qa);
                qa = pk_fma(U2p[cp][2], hC2[cp], qa);
                ra = pk_fma(U3p[cp][0], hA2[cp], ra);
                ra = pk_fma(U3p[cp][1], hB2[cp], ra);
                ra = pk_fma(U3p[cp][2], hC2[cp], ra);
            }
            float pp_ = rsum16(pa[0] + pa[1]);
            float qq_ = rsum16(qa[0] + qa[1]);
            float rr_ = rsum16(ra[0] + ra[1]);
            float P = pp_ + cb1, Q = qq_ + cb2, R = rr_ + cb3;
            float hv = fmaxf(fmaf(P, fast_sigmoid(Q), R), 0.f);
            if ((tid & 15) == 0) dst[w * NODES + node] = f2bf(fmaf(hv, s2, bb2));
        }
        hA2[0] = hB2[0]; hA2[1] = hB2[1];
        hB2[0] = hC2[0]; hB2[1] = hC2[1];
    }
}

// ---------------- FC1 MFMA GEMM, B read directly from f32 fcW ----------------
#define KSPL1 8
#define KCH1  (KP1 / KSPL1)  // 800
__global__ __launch_bounds__(256) void k_gemm1f(const short* __restrict__ Ab,
                                                const float* __restrict__ fcW,
                                                float* __restrict__ part) {
    int lane = threadIdx.x & 63, wv = threadIdx.x >> 6;
    int r = lane & 15, kg = lane >> 4;
    int nb = blockIdx.x * 64, sp = blockIdx.y;

    f32x4 acc[2][4] = {};
    const short* a0 = Ab + (size_t)(wv * 32 + r) * KP1;
    const short* a1 = a0 + (size_t)16 * KP1;

    int k0 = sp * KCH1 + kg * 8;
    const float* wp = fcW + (size_t)k0 * FC1_OUT + nb + r;
    bool tailblk = (sp == KSPL1 - 1);

#pragma unroll 1
    for (int s = 0; s < KCH1 / 32; s++, k0 += 32) {
        short8 av0 = *(const short8*)(a0 + k0);
        short8 av1 = *(const short8*)(a1 + k0);
        short8 bv[4];
        if (tailblk && s == KCH1 / 32 - 1) {
#pragma unroll
            for (int f = 0; f < 4; f++) {
                float wf[8];
#pragma unroll
                for (int i = 0; i < 8; i++)
                    wf[i] = (k0 + i < FC1_IN) ? wp[(size_t)i * FC1_OUT + f * 16] : 0.f;
                i32x4 pk;
                pk[0] = cvtpk(wf[0], wf[1]);
                pk[1] = cvtpk(wf[2], wf[3]);
                pk[2] = cvtpk(wf[4], wf[5]);
                pk[3] = cvtpk(wf[6], wf[7]);
                bv[f] = __builtin_bit_cast(short8, pk);
            }
        } else {
#pragma unroll
            for (int f = 0; f < 4; f++) {
                float wf[8];
#pragma unroll
                for (int i = 0; i < 8; i++)
                    wf[i] = wp[(size_t)i * FC1_OUT + f * 16];
                i32x4 pk;
                pk[0] = cvtpk(wf[0], wf[1]);
                pk[1] = cvtpk(wf[2], wf[3]);
                pk[2] = cvtpk(wf[4], wf[5]);
                pk[3] = cvtpk(wf[6], wf[7]);
                bv[f] = __builtin_bit_cast(short8, pk);
            }
        }
        acc[0][0] = __builtin_amdgcn_mfma_f32_16x16x32_bf16(av0, bv[0], acc[0][0], 0, 0, 0);
        acc[1][0] = __builtin_amdgcn_mfma_f32_16x16x32_bf16(av1, bv[0], acc[1][0], 0, 0, 0);
        acc[0][1] = __builtin_amdgcn_mfma_f32_16x16x32_bf16(av0, bv[1], acc[0][1], 0, 0, 0);
        acc[1][1] = __builtin_amdgcn_mfma_f32_16x16x32_bf16(av1, bv[1], acc[1][1], 0, 0, 0);
        acc[0][2] = __builtin_amdgcn_mfma_f32_16x16x32_bf16(av0, bv[2], acc[0][2], 0, 0, 0);
        acc[1][2] = __builtin_amdgcn_mfma_f32_16x16x32_bf16(av1, bv[2], acc[1][2], 0, 0, 0);
        acc[0][3] = __builtin_amdgcn_mfma_f32_16x16x32_bf16(av0, bv[3], acc[0][3], 0, 0, 0);
        acc[1][3] = __builtin_amdgcn_mfma_f32_16x16x32_bf16(av1, bv[3], acc[1][3], 0, 0, 0);
        wp += (size_t)32 * FC1_OUT;
    }

    float* dst = part + (size_t)sp * BATCH * FC1_OUT;
#pragma unroll
    for (int m = 0; m < 2; m++)
#pragma unroll
        for (int f = 0; f < 4; f++)
#pragma unroll
            for (int j = 0; j < 4; j++) {
                int row = wv * 32 + m * 16 + kg * 4 + j;
                int col = nb + f * 16 + r;
                dst[(size_t)row * FC1_OUT + col] = acc[m][f][j];
            }
}

// reduce split-K + bias + ReLU -> bf16 activations for FC2
__global__ __launch_bounds__(256) void k_reduce1(const float* __restrict__ part,
                                                 const float* __restrict__ bias,
                                                 short* __restrict__ Ab2) {
    int idx = blockIdx.x * 256 + threadIdx.x;
    int o = idx & (FC1_OUT - 1);
    float s = bias[o];
#pragma unroll
    for (int sp = 0; sp < KSPL1; sp++) s += part[(size_t)sp * BATCH * FC1_OUT + idx];
    Ab2[idx] = f2bf(fmaxf(s, 0.f));
}

// ---------------- FC2 MFMA GEMM, B read directly from f32 fc4W ----------------
#define KSPL2 8
#define KCH2  (FC1_OUT / KSPL2)  // 256
__global__ __launch_bounds__(256) void k_gemm2f(const short* __restrict__ Ab,
                                                const float* __restrict__ fc4W,
                                                float* __restrict__ part) {
    int lane = threadIdx.x & 63, wv = threadIdx.x >> 6;
    int r = lane & 15, kg = lane >> 4;
    int nb = blockIdx.x * 16, sp = blockIdx.y;

    f32x4 acc[2] = {};
    const short* a0 = Ab + (size_t)(wv * 32 + r) * FC1_OUT;
    const short* a1 = a0 + (size_t)16 * FC1_OUT;
    int col = nb + r;
    int colc = (col < FC2_OUT) ? col : FC2_OUT - 1;  // clamp; pad cols never read

    int k0 = sp * KCH2 + kg * 8;
    const float* wp = fc4W + (size_t)k0 * FC2_OUT + colc;
#pragma unroll 1
    for (int s = 0; s < KCH2 / 32; s++, k0 += 32) {
        short8 av0 = *(const short8*)(a0 + k0);
        short8 av1 = *(const short8*)(a1 + k0);
        float wf[8];
#pragma unroll
        for (int i = 0; i < 8; i++) wf[i] = wp[(size_t)i * FC2_OUT];
        i32x4 pk;
        pk[0] = cvtpk(wf[0], wf[1]);
        pk[1] = cvtpk(wf[2], wf[3]);
        pk[2] = cvtpk(wf[4], wf[5]);
        pk[3] = cvtpk(wf[6], wf[7]);
        short8 bv = __builtin_bit_cast(short8, pk);
        acc[0] = __builtin_amdgcn_mfma_f32_16x16x32_bf16(av0, bv, acc[0], 0, 0, 0);
        acc[1] = __builtin_amdgcn_mfma_f32_16x16x32_bf16(av1, bv, acc[1], 0, 0, 0);
        wp += (size_t)32 * FC2_OUT;
    }

    float* dst = part + (size_t)sp * BATCH * NP2;
#pragma unroll
    for (int m = 0; m < 2; m++)
#pragma unroll
        for (int j = 0; j < 4; j++) {
            int row = wv * 32 + m * 16 + kg * 4 + j;
            dst[(size_t)row * NP2 + col] = acc[m][j];
        }
}

__global__ __launch_bounds__(256) void k_reduce2(const float* __restrict__ part,
                                                 const float* __restrict__ bias,
                                                 float* __restrict__ out) {
    int idx = blockIdx.x * 256 + threadIdx.x;
    if (idx >= BATCH * NP2) return;
    int b = idx / NP2, o = idx % NP2;
    float s = 0.f;
#pragma unroll
    for (int sp = 0; sp < KSPL2; sp++) s += part[(size_t)sp * BATCH * NP2 + idx];
    if (o < FC2_OUT) out[(size_t)b * FC2_OUT + o] = s + bias[o];
}

extern "C" void kernel_launch(void* const* d_in, const int* in_sizes, int n_in,
                              void* d_out, int out_size, void* d_ws, size_t ws_size,
                              hipStream_t stream) {
    const float* data_x = (const float*)d_in[0];
    const int* ei = (const int*)d_in[1];
    const float* ew = (const float*)d_in[2];
    const float* tc1w1 = (const float*)d_in[3];
    const float* tc1b1 = (const float*)d_in[4];
    const float* tc1w2 = (const float*)d_in[5];
    const float* tc1b2 = (const float*)d_in[6];
    const float* tc1w3 = (const float*)d_in[7];
    const float* tc1b3 = (const float*)d_in[8];
    const float* W0 = (const float*)d_in[9];
    const float* gb0 = (const float*)d_in[10];
    const float* bn0g = (const float*)d_in[11];
    const float* bn0b = (const float*)d_in[12];
    const float* W1 = (const float*)d_in[13];
    const float* gb1 = (const float*)d_in[14];
    const float* bn1g = (const float*)d_in[15];
    const float* bn1b = (const float*)d_in[16];
    const float* tc2w1 = (const float*)d_in[17];
    const float* tc2b1 = (const float*)d_in[18];
    const float* tc2w2 = (const float*)d_in[19];
    const float* tc2b2 = (const float*)d_in[20];
    const float* tc2w3 = (const float*)d_in[21];
    const float* tc2b3 = (const float*)d_in[22];
    const float* bn2g = (const float*)d_in[23];
    const float* bn2b = (const float*)d_in[24];
    const float* fcW = (const float*)d_in[25];
    const float* fcb = (const float*)d_in[26];
    const float* fc4W = (const float*)d_in[27];
    const float* fc4b = (const float*)d_in[28];
    float* out = (float*)d_out;

    char* ws = (char*)d_ws;
    // persistent: x2 (gfeat source) + Ab (FC1 bf16 activations)
    float* x2 = (float*)(ws + 0);                  // 9,961,472 B
    short* Ab = (short*)(ws + 9961472);            // 1,638,400 B
    const size_t ARENA = 9961472 + 1638400;        // 11,599,872

    // arena A (graph phase)
    size_t off = ARENA;
    auto alloc = [&](size_t bytes) -> void* {
        void* p = ws + off;
        off = (off + bytes + 255) & ~(size_t)255;
        return p;
    };
    unsigned* bucket = (unsigned*)alloc((size_t)NN * BCAP * 4);  // 9.96 MB packed
    int* cnt = (int*)alloc((size_t)NN * 4);
    float* dinv = (float*)alloc((size_t)NN * 4);
    unsigned short* Xb = (unsigned short*)alloc((size_t)NN * 32 * 2);  // 2.5 MB
    unsigned short* h1 = (unsigned short*)alloc((size_t)NN * HID * 2); // 5 MB

    // x2t overlaps arena A (bucket region dead after gatherB)
    float* x2t = (float*)(ws + ARENA);             // 9,961,472 B

    // arena C (FC phase) — overlaps arena A and x2t, used only after temporal
    off = ARENA + 9961472;
    float* part1 = (float*)alloc((size_t)KSPL1 * BATCH * FC1_OUT * 4);
    short* Ab2 = (short*)alloc((size_t)BATCH * FC1_OUT * 2);
    float* part2 = (float*)alloc((size_t)KSPL2 * BATCH * NP2 * 4);
    (void)ws_size; (void)in_sizes; (void)n_in; (void)out_size;

    // ---- bucketed edge build (packed u32 entries) ----
    hipMemsetAsync(cnt, 0, (size_t)NN * 4, stream);
    k_bucket<<<(NE + 255) / 256, 256, 0, stream>>>(ei, ew, cnt, bucket);

    // ---- GCN ----
    k_cvtX<<<NN / 8, 256, 0, stream>>>(data_x, cnt, bucket, Xb, dinv);
    k_gather20<<<NN / 4, 256, 0, stream>>>(cnt, bucket, dinv, Xb, W0, gb0, bn0g,
                                           bn0b, W1, h1);
    k_gatherB<<<NN / 4, 256, 0, stream>>>(cnt, bucket, dinv, h1, gb1, bn1g, bn1b, x2);

    // ---- transpose x2 for coalesced gfeat ----
    k_xpose<<<NN / 64, 256, 0, stream>>>(x2, x2t);

    // ---- temporal (rolling-window, packed fp32; gfeat via x2t) ----
    hipMemsetAsync(Ab, 0, (size_t)BATCH * KP1 * 2, stream);  // zero K-padding
    k_temporal2<<<NN / 16, 256, 0, stream>>>(data_x, x2t, tc1w1, tc1b1, tc1w2, tc1b2,
                                             tc1w3, tc1b3, tc2w1, tc2b1, tc2w2, tc2b2,
                                             tc2w3, tc2b3, bn2g, bn2b, Ab);

    // ---- FC (bf16 MFMA, packed-convert B) ----
    {
        dim3 g(FC1_OUT / 64, KSPL1);
        k_gemm1f<<<g, 256, 0, stream>>>(Ab, fcW, part1);
    }
    k_reduce1<<<BATCH * FC1_OUT / 256, 256, 0, stream>>>(part1, fcb, Ab2);
    {
        dim3 g(NP2 / 16, KSPL2);
        k_gemm2f<<<g, 256, 0, stream>>>(Ab2, fc4W, part2);
    }
    k_reduce2<<<(BATCH * NP2 + 255) / 256, 256, 0, stream>>>(part2, fc4b, out);
}

// Round 15
// 174.603 us; speedup vs baseline: 1.3115x; 1.0264x over previous
//
#include <hip/hip_runtime.h>

#define NODES   304
#define BATCH   128
#define TSTEPS  20
#define HID     64
#define GCNIN   20
#define NN      (BATCH*NODES)      // 38912
#define NE      (NN*16)            // 622592
#define SEGSZ   (NN/4)             // 9728 (row-quarter for L2 phasing)
#define BCAP    64                 // bucket capacity per col
#define FC1_IN  (21*NODES)         // 6384
#define KP1     6400               // FC1_IN padded to /32
#define FC1_OUT 2048
#define FC2_OUT 300
#define NP2     304                // FC2_OUT padded to /16
#define BN_EPS  1e-5f

typedef __attribute__((ext_vector_type(8))) short short8;
typedef __attribute__((ext_vector_type(4))) float f32x4;
typedef __attribute__((ext_vector_type(2))) float f32x2;
typedef __attribute__((ext_vector_type(4))) int i32x4;

static __device__ __forceinline__ short f2bf(float x) {
    unsigned u = __float_as_uint(x);
    unsigned r = (u + 0x7FFF + ((u >> 16) & 1)) >> 16;  // RNE
    return (short)r;
}
static __device__ __forceinline__ float bf2f(unsigned short v) {
    return __uint_as_float((unsigned)v << 16);
}

// packed f32->bf16 convert (1 instr for 2 values, RNE); low half = a
static __device__ __forceinline__ int cvtpk(float a, float b) {
    int r;
    asm("v_cvt_pk_bf16_f32 %0, %1, %2" : "=v"(r) : "v"(a), "v"(b));
    return r;
}

static __device__ __forceinline__ float fast_sigmoid(float q) {
    return __builtin_amdgcn_rcpf(1.f + __expf(-q));
}

// packed fp32 FMA (VOP3P)
static __device__ __forceinline__ f32x2 pk_fma(f32x2 a, f32x2 b, f32x2 c) {
    f32x2 d;
    asm("v_pk_fma_f32 %0, %1, %2, %3" : "=v"(d) : "v"(a), "v"(b), "v"(c));
    return d;
}

// DPP row_ror add (VALU pipe, no DS ops)
template <int C>
static __device__ __forceinline__ float dppadd(float v) {
    return v + __int_as_float(
        __builtin_amdgcn_update_dpp(0, __float_as_int(v), C, 0xF, 0xF, false));
}
static __device__ __forceinline__ float rsum16(float v) {
    v = dppadd<0x128>(v);
    v = dppadd<0x124>(v);
    v = dppadd<0x122>(v);
    v = dppadd<0x121>(v);
    return v;
}

// ------- bucketed edge build: ONE global atomic/edge; packed u32 entries -------
// entry = (bf16(weight) << 16) | row16   (row < 38912 < 65536)
__global__ void k_bucket(const int* __restrict__ ei, const float* __restrict__ ew,
                         int* __restrict__ cnt, unsigned* __restrict__ bucket) {
    int e = blockIdx.x * blockDim.x + threadIdx.x;
    if (e < NE) {
        int c = ei[NE + e];
        int slot = atomicAdd(&cnt[c], 1);
        if (slot < BCAP) {
            unsigned v = ((unsigned)(unsigned short)f2bf(ew[e]) << 16) |
                         (unsigned)ei[e];
            bucket[((size_t)c << 6) + slot] = v;
        }
    }
}

// ---- Xb = dinv * data_x as bf16 [NN][32] (64B rows); also computes dinv ----
__global__ __launch_bounds__(256) void k_cvtX(const float* __restrict__ X,
                                              const int* __restrict__ cnt,
                                              const unsigned* __restrict__ bucket,
                                              unsigned short* __restrict__ Xb,
                                              float* __restrict__ dinv) {
    int wv = threadIdx.x >> 5, f = threadIdx.x & 31;  // 8 nodes x 32 lanes
    int n = blockIdx.x * 8 + wv;
    __shared__ float rs[8][2];

    unsigned e0 = bucket[((size_t)n << 6) + f];
    unsigned e1 = bucket[((size_t)n << 6) + 32 + f];
    int deg = cnt[n];
    float xv = (f < GCNIN) ? X[(size_t)n * GCNIN + f] : 0.f;

    int dcap = deg < BCAP ? deg : BCAP;
    float s = ((f < dcap) ? bf2f((unsigned short)(e0 >> 16)) : 0.f) +
              ((32 + f < dcap) ? bf2f((unsigned short)(e1 >> 16)) : 0.f);
    s = rsum16(s);
    if ((f & 15) == 0) rs[wv][f >> 4] = s;
    __syncthreads();

    float dv = rsqrtf(fmaxf(1.f + rs[wv][0] + rs[wv][1], 1e-12f));
    if (f == 0) dinv[n] = dv;
    Xb[(size_t)n * 32 + f] = (f < GCNIN) ? (unsigned short)f2bf(xv * dv)
                                         : (unsigned short)0;
}

// ballot-partition the wave's staged edges by row-quarter (L2 phasing)
static __device__ __forceinline__ void stage_partition(
    int deg, unsigned e, int f, int wv, int (*sIdx)[BCAP], float (*sWt)[BCAP],
    int& dcap) {
    dcap = deg < BCAP ? deg : BCAP;
    bool valid = f < dcap;
    int row = (int)(e & 0xffffu);
    float w = bf2f((unsigned short)(e >> 16));
    int q = (row >= SEGSZ) + (row >= 2 * SEGSZ) + (row >= 3 * SEGSZ);
    unsigned long long b0 = __ballot(valid && q == 0);
    unsigned long long b1 = __ballot(valid && q == 1);
    unsigned long long b2 = __ballot(valid && q == 2);
    unsigned long long b3 = __ballot(valid && q == 3);
    unsigned long long lmask = (1ULL << f) - 1;
    int pos = 0;
    if (q > 0) pos += __popcll(b0);
    if (q > 1) pos += __popcll(b1);
    if (q > 2) pos += __popcll(b2);
    unsigned long long mybal = (q == 0) ? b0 : (q == 1) ? b1 : (q == 2) ? b2 : b3;
    pos += __popcll(mybal & lmask);
    if (valid) {
        sIdx[wv][pos] = row;
        sWt[wv][pos] = w;
    }
}

// ---- layer0: gather RAW 20-dim feats (L2-resident 2.5MB table) + @W0 + BN +
//      ReLU + matvec @W1 -> h1 prescaled bf16 ----
__global__ __launch_bounds__(256) void k_gather20(const int* __restrict__ cnt,
                                                  const unsigned* __restrict__ bucket,
                                                  const float* __restrict__ dinv,
                                                  const unsigned short* __restrict__ Xb,
                                                  const float* __restrict__ W0,
                                                  const float* __restrict__ gb,
                                                  const float* __restrict__ bng,
                                                  const float* __restrict__ bnb,
                                                  const float* __restrict__ W1,
                                                  unsigned short* __restrict__ H1) {
    int wv = threadIdx.x >> 6, f = threadIdx.x & 63;
    int c = blockIdx.x * 4 + wv;
    int g = f >> 4, r = f & 15;  // edge-group, channel-pair lane
    __shared__ int sIdx[4][BCAP];
    __shared__ float sWt[4][BCAP];
    __shared__ float agg[4][32];
    __shared__ float xs[4][HID];

    unsigned be = bucket[((size_t)c << 6) + f];
    int deg = cnt[c];
    float dc = dinv[c];
    unsigned selfv = *(const unsigned*)(Xb + (size_t)c * 32 + 2 * r);

    int dcap;
    stage_partition(deg, be, f, wv, sIdx, sWt, dcap);
    __syncthreads();

    f32x2 acc2;
    acc2[0] = 0.f;
    acc2[1] = 0.f;
    for (int base = 0; base < dcap; base += 16) {
        int idx[4];
        float w[4];
#pragma unroll
        for (int i = 0; i < 4; i++) {
            int l = base + (i << 2) + g;
            int lc = (l < dcap) ? l : dcap - 1;
            idx[i] = sIdx[wv][lc];
            w[i] = (l < dcap) ? sWt[wv][lc] : 0.f;
        }
        unsigned vv[4];
#pragma unroll
        for (int i = 0; i < 4; i++)
            vv[i] = *(const unsigned*)(Xb + (size_t)idx[i] * 32 + 2 * r);
#pragma unroll
        for (int i = 0; i < 4; i++) {
            acc2[0] = fmaf(bf2f((unsigned short)(vv[i] & 0xffff)), w[i], acc2[0]);
            acc2[1] = fmaf(bf2f((unsigned short)(vv[i] >> 16)), w[i], acc2[1]);
        }
    }
    acc2[0] += __shfl_xor(acc2[0], 16);
    acc2[0] += __shfl_xor(acc2[0], 32);
    acc2[1] += __shfl_xor(acc2[1], 16);
    acc2[1] += __shfl_xor(acc2[1], 32);
    if (g == 0) {
        agg[wv][2 * r] = acc2[0] + bf2f((unsigned short)(selfv & 0xffff));
        agg[wv][2 * r + 1] = acc2[1] + bf2f((unsigned short)(selfv >> 16));
    }
    __syncthreads();

    float v = 0.f;
#pragma unroll
    for (int k = 0; k < GCNIN; k++) v = fmaf(agg[wv][k], W0[k * HID + f], v);
    float scale = bng[f] * rsqrtf(1.f + BN_EPS);
    float y = fmaxf(fmaf(v * dc + gb[f], scale, bnb[f]), 0.f);

    xs[wv][f] = y;
    __syncthreads();
    float h = 0.f;
#pragma unroll
    for (int k4 = 0; k4 < HID / 4; k4++) {
        float4 xv = *(const float4*)&xs[wv][k4 * 4];
        h = fmaf(xv.x, W1[(k4 * 4 + 0) * HID + f], h);
        h = fmaf(xv.y, W1[(k4 * 4 + 1) * HID + f], h);
        h = fmaf(xv.z, W1[(k4 * 4 + 2) * HID + f], h);
        h = fmaf(xv.w, W1[(k4 * 4 + 3) * HID + f], h);
    }
    H1[(size_t)c * HID + f] = (unsigned short)f2bf(h * dc);  // pre-scaled
}

// ---- layer1 gather + BN + ReLU, TRANSPOSED output written directly:
//      x2t[h][n] = x2[n][h]  (fused k_xpose; x2 never materialized) ----
__global__ __launch_bounds__(256) void k_gatherBT(const int* __restrict__ cnt,
                                                  const unsigned* __restrict__ bucket,
                                                  const float* __restrict__ dinv,
                                                  const unsigned short* __restrict__ H,
                                                  const float* __restrict__ gb,
                                                  const float* __restrict__ bng,
                                                  const float* __restrict__ bnb,
                                                  float* __restrict__ x2t) {
    int wv = threadIdx.x >> 6, f = threadIdx.x & 63;
    int tid = threadIdx.x;
    int c = blockIdx.x * 4 + wv;
    int g = f >> 4, r = f & 15;  // edge-group, channel-quad lane
    __shared__ int sIdx[4][BCAP];
    __shared__ float sWt[4][BCAP];
    __shared__ float xs2[4][HID];  // [node-in-block][channel]

    unsigned be = bucket[((size_t)c << 6) + f];
    int deg = cnt[c];
    float dc = dinv[c];
    ushort4 selfv = *(const ushort4*)(H + (size_t)c * HID + 4 * r);

    int dcap;
    stage_partition(deg, be, f, wv, sIdx, sWt, dcap);
    __syncthreads();

    float a0 = 0.f, a1 = 0.f, a2 = 0.f, a3 = 0.f;
    for (int base = 0; base < dcap; base += 16) {
        int idx[4];
        float w[4];
#pragma unroll
        for (int i = 0; i < 4; i++) {
            int l = base + (i << 2) + g;
            int lc = (l < dcap) ? l : dcap - 1;
            idx[i] = sIdx[wv][lc];
            w[i] = (l < dcap) ? sWt[wv][lc] : 0.f;
        }
        ushort4 hv[4];
#pragma unroll
        for (int i = 0; i < 4; i++)
            hv[i] = *(const ushort4*)(H + (size_t)idx[i] * HID + 4 * r);
#pragma unroll
        for (int i = 0; i < 4; i++) {
            a0 = fmaf(bf2f(hv[i].x), w[i], a0);
            a1 = fmaf(bf2f(hv[i].y), w[i], a1);
            a2 = fmaf(bf2f(hv[i].z), w[i], a2);
            a3 = fmaf(bf2f(hv[i].w), w[i], a3);
        }
    }
    a0 += __shfl_xor(a0, 16); a0 += __shfl_xor(a0, 32);
    a1 += __shfl_xor(a1, 16); a1 += __shfl_xor(a1, 32);
    a2 += __shfl_xor(a2, 16); a2 += __shfl_xor(a2, 32);
    a3 += __shfl_xor(a3, 16); a3 += __shfl_xor(a3, 32);

    if (g == 0) {
        float4 scv = *(const float4*)&bng[4 * r];
        float4 bbv = *(const float4*)&bnb[4 * r];
        float4 gbv = *(const float4*)&gb[4 * r];
        float rr = rsqrtf(1.f + BN_EPS);
        xs2[wv][4 * r + 0] =
            fmaxf(fmaf((a0 + bf2f(selfv.x)) * dc + gbv.x, scv.x * rr, bbv.x), 0.f);
        xs2[wv][4 * r + 1] =
            fmaxf(fmaf((a1 + bf2f(selfv.y)) * dc + gbv.y, scv.y * rr, bbv.y), 0.f);
        xs2[wv][4 * r + 2] =
            fmaxf(fmaf((a2 + bf2f(selfv.z)) * dc + gbv.z, scv.z * rr, bbv.z), 0.f);
        xs2[wv][4 * r + 3] =
            fmaxf(fmaf((a3 + bf2f(selfv.w)) * dc + gbv.w, scv.w * rr, bbv.w), 0.f);
    }
    __syncthreads();

    // transposed write: thread tid -> row h = tid>>2, node-in-block nn = tid&3.
    // Consecutive tids write consecutive addresses (16B quads); adjacent blocks
    // fill adjacent quads of the same 64B lines -> L2 merges.
    int h = tid >> 2, nn = tid & 3;
    x2t[(size_t)h * NN + blockIdx.x * 4 + nn] = xs2[nn][h];
}

// unpack 12 contiguous LDS floats (ch c0..c0+3 × 3 taps) into packed pairs
static __device__ __forceinline__ void load12(const float* base, f32x2 P[2][3]) {
    float4 f0 = *(const float4*)(base);
    float4 f1 = *(const float4*)(base + 4);
    float4 f2 = *(const float4*)(base + 8);
    P[0][0][0] = f0.x; P[0][0][1] = f0.w;
    P[0][1][0] = f0.y; P[0][1][1] = f1.x;
    P[0][2][0] = f0.z; P[0][2][1] = f1.y;
    P[1][0][0] = f1.z; P[1][0][1] = f2.y;
    P[1][1][0] = f1.w; P[1][1][1] = f2.z;
    P[1][2][0] = f2.x; P[1][2][1] = f2.w;
}

// ---------------- fused temporal: packed-fp32, LDS weights, 16 pairs/block ----
__global__ __launch_bounds__(256) void k_temporal2(
    const float* __restrict__ data_x, const float* __restrict__ x2t,
    const float* __restrict__ w1, const float* __restrict__ b1,
    const float* __restrict__ w2, const float* __restrict__ b2,
    const float* __restrict__ w3, const float* __restrict__ b3,
    const float* __restrict__ v1, const float* __restrict__ vb1,
    const float* __restrict__ v2, const float* __restrict__ vb2,
    const float* __restrict__ v3, const float* __restrict__ vb3,
    const float* __restrict__ bn2g, const float* __restrict__ bn2b,
    short* __restrict__ Ab) {
    int bn0 = blockIdx.x * 16;
    int b = bn0 / NODES, node0 = bn0 % NODES;
    int tid = threadIdx.x;
    int p = tid >> 4;
    int c0 = (tid & 15) << 2;
    int node = node0 + p;

    __shared__ float xs[16][22];
    __shared__ float wlds[1344];

    if (tid < 192) {
        wlds[tid] = w1[tid];
        wlds[192 + tid] = w2[tid];
        wlds[384 + tid] = w3[tid];
        wlds[576 + tid] = v1[tid];
        wlds[768 + tid] = v2[tid];
        wlds[960 + tid] = v3[tid];
    }
    if (tid < 64) {
        wlds[1152 + tid] = b1[tid];
        wlds[1216 + tid] = b2[tid];
        wlds[1280 + tid] = b3[tid];
    }
    for (int i = tid; i < 320; i += 256) {
        int t = i >> 4, pp = i & 15;
        xs[pp][t + 1] = data_x[b * (TSTEPS * NODES) + t * NODES + node0 + pp];
    }
    if (tid < 16) { xs[tid][0] = 0.f; xs[tid][21] = 0.f; }

    float cb1 = vb1[0], cb2 = vb2[0], cb3 = vb3[0];
    float s2 = bn2g[node] * rsqrtf(1.f + BN_EPS);
    float bb2 = bn2b[node];
    short* dst = Ab + (size_t)b * KP1;

    __syncthreads();

    f32x2 A1p[2][3], A2p[2][3], A3p[2][3], B1p[2], B2p[2], B3p[2];
    f32x2 U1p[2][3], U2p[2][3], U3p[2][3];
    load12(&wlds[0 + c0 * 3], A1p);
    load12(&wlds[192 + c0 * 3], A2p);
    load12(&wlds[384 + c0 * 3], A3p);
    load12(&wlds[576 + c0 * 3], U1p);
    load12(&wlds[768 + c0 * 3], U2p);
    load12(&wlds[960 + c0 * 3], U3p);
    {
        float4 t1 = *(const float4*)&wlds[1152 + c0];
        float4 t2 = *(const float4*)&wlds[1216 + c0];
        float4 t3 = *(const float4*)&wlds[1280 + c0];
        B1p[0][0] = t1.x; B1p[0][1] = t1.y; B1p[1][0] = t1.z; B1p[1][1] = t1.w;
        B2p[0][0] = t2.x; B2p[0][1] = t2.y; B2p[1][0] = t2.z; B2p[1][1] = t2.w;
        B3p[0][0] = t3.x; B3p[0][1] = t3.y; B3p[1][0] = t3.z; B3p[1][1] = t3.w;
    }

    f32x2 hA2[2] = {}, hB2[2] = {}, hC2[2];
    float xr0 = xs[p][0], xr1 = xs[p][1];

#pragma unroll
    for (int j = 0; j <= 21; j++) {
        if (j < 20) {
            float xr2 = xs[p][j + 2];
            f32x2 x0d, x1d, x2d;
            x0d[0] = xr0; x0d[1] = xr0;
            x1d[0] = xr1; x1d[1] = xr1;
            x2d[0] = xr2; x2d[1] = xr2;
#pragma unroll
            for (int cp = 0; cp < 2; cp++) {
                f32x2 pv = pk_fma(A1p[cp][2], x2d,
                            pk_fma(A1p[cp][1], x1d, pk_fma(A1p[cp][0], x0d, B1p[cp])));
                f32x2 qv = pk_fma(A2p[cp][2], x2d,
                            pk_fma(A2p[cp][1], x1d, pk_fma(A2p[cp][0], x0d, B2p[cp])));
                f32x2 rv = pk_fma(A3p[cp][2], x2d,
                            pk_fma(A3p[cp][1], x1d, pk_fma(A3p[cp][0], x0d, B3p[cp])));
                hC2[cp][0] = fmaxf(fmaf(pv[0], fast_sigmoid(qv[0]), rv[0]), 0.f);
                hC2[cp][1] = fmaxf(fmaf(pv[1], fast_sigmoid(qv[1]), rv[1]), 0.f);
            }
            xr0 = xr1;
            xr1 = xr2;
        } else if (j == 20) {
            const float4 gv = *(const float4*)(x2t + (size_t)(b >> 1) * NN +
                                               (b & 1) * (NODES * HID) + node * HID + c0);
            hC2[0][0] = fmaxf(gv.x, 0.f);
            hC2[0][1] = fmaxf(gv.y, 0.f);
            hC2[1][0] = fmaxf(gv.z, 0.f);
            hC2[1][1] = fmaxf(gv.w, 0.f);
        } else {
            hC2[0][0] = 0.f; hC2[0][1] = 0.f;
            hC2[1][0] = 0.f; hC2[1][1] = 0.f;
        }
        if (j >= 1) {
            int w = j - 1;
            f32x2 pa, qa, ra;
            pa[0] = 0.f; pa[1] = 0.f;
            qa[0] = 0.f; qa[1] = 0.f;
            ra[0] = 0.f; ra[1] = 0.f;
#pragma unroll
            for (int cp = 0; cp < 2; cp++) {
                pa = pk_fma(U1p[cp][0], hA2[cp], pa);
                pa = pk_fma(U1p[cp][1], hB2[cp], pa);
                pa = pk_fma(U1p[cp][2], hC2[cp], pa);
                qa = pk_fma(U2p[cp][0], hA2[cp], qa);
                qa = pk_fma(U2p[cp][1], hB2[cp], qa);
                qa = pk_fma(U2p[cp][2], hC2[cp], qa);
                ra = pk_fma(U3p[cp][0], hA2[cp], ra);
                ra = pk_fma(U3p[cp][1], hB2[cp], ra);
                ra = pk_fma(U3p[cp][2], hC2[cp], ra);
            }
            float pp_ = rsum16(pa[0] + pa[1]);
            float qq_ = rsum16(qa[0] + qa[1]);
            float rr_ = rsum16(ra[0] + ra[1]);
            float P = pp_ + cb1, Q = qq_ + cb2, R = rr_ + cb3;
            float hv = fmaxf(fmaf(P, fast_sigmoid(Q), R), 0.f);
            if ((tid & 15) == 0) dst[w * NODES + node] = f2bf(fmaf(hv, s2, bb2));
        }
        hA2[0] = hB2[0]; hA2[1] = hB2[1];
        hB2[0] = hC2[0]; hB2[1] = hC2[1];
    }
}

// ---------------- FC1 MFMA GEMM, B read directly from f32 fcW ----------------
#define KSPL1 8
#define KCH1  (KP1 / KSPL1)  // 800
__global__ __launch_bounds__(256) void k_gemm1f(const short* __restrict__ Ab,
                                                const float* __restrict__ fcW,
                                                float* __restrict__ part) {
    int lane = threadIdx.x & 63, wv = threadIdx.x >> 6;
    int r = lane & 15, kg = lane >> 4;
    int nb = blockIdx.x * 64, sp = blockIdx.y;

    f32x4 acc[2][4] = {};
    const short* a0 = Ab + (size_t)(wv * 32 + r) * KP1;
    const short* a1 = a0 + (size_t)16 * KP1;

    int k0 = sp * KCH1 + kg * 8;
    const float* wp = fcW + (size_t)k0 * FC1_OUT + nb + r;
    bool tailblk = (sp == KSPL1 - 1);

#pragma unroll 1
    for (int s = 0; s < KCH1 / 32; s++, k0 += 32) {
        short8 av0 = *(const short8*)(a0 + k0);
        short8 av1 = *(const short8*)(a1 + k0);
        short8 bv[4];
        if (tailblk && s == KCH1 / 32 - 1) {
#pragma unroll
            for (int f = 0; f < 4; f++) {
                float wf[8];
#pragma unroll
                for (int i = 0; i < 8; i++)
                    wf[i] = (k0 + i < FC1_IN) ? wp[(size_t)i * FC1_OUT + f * 16] : 0.f;
                i32x4 pk;
                pk[0] = cvtpk(wf[0], wf[1]);
                pk[1] = cvtpk(wf[2], wf[3]);
                pk[2] = cvtpk(wf[4], wf[5]);
                pk[3] = cvtpk(wf[6], wf[7]);
                bv[f] = __builtin_bit_cast(short8, pk);
            }
        } else {
#pragma unroll
            for (int f = 0; f < 4; f++) {
                float wf[8];
#pragma unroll
                for (int i = 0; i < 8; i++)
                    wf[i] = wp[(size_t)i * FC1_OUT + f * 16];
                i32x4 pk;
                pk[0] = cvtpk(wf[0], wf[1]);
                pk[1] = cvtpk(wf[2], wf[3]);
                pk[2] = cvtpk(wf[4], wf[5]);
                pk[3] = cvtpk(wf[6], wf[7]);
                bv[f] = __builtin_bit_cast(short8, pk);
            }
        }
        acc[0][0] = __builtin_amdgcn_mfma_f32_16x16x32_bf16(av0, bv[0], acc[0][0], 0, 0, 0);
        acc[1][0] = __builtin_amdgcn_mfma_f32_16x16x32_bf16(av1, bv[0], acc[1][0], 0, 0, 0);
        acc[0][1] = __builtin_amdgcn_mfma_f32_16x16x32_bf16(av0, bv[1], acc[0][1], 0, 0, 0);
        acc[1][1] = __builtin_amdgcn_mfma_f32_16x16x32_bf16(av1, bv[1], acc[1][1], 0, 0, 0);
        acc[0][2] = __builtin_amdgcn_mfma_f32_16x16x32_bf16(av0, bv[2], acc[0][2], 0, 0, 0);
        acc[1][2] = __builtin_amdgcn_mfma_f32_16x16x32_bf16(av1, bv[2], acc[1][2], 0, 0, 0);
        acc[0][3] = __builtin_amdgcn_mfma_f32_16x16x32_bf16(av0, bv[3], acc[0][3], 0, 0, 0);
        acc[1][3] = __builtin_amdgcn_mfma_f32_16x16x32_bf16(av1, bv[3], acc[1][3], 0, 0, 0);
        wp += (size_t)32 * FC1_OUT;
    }

    float* dst = part + (size_t)sp * BATCH * FC1_OUT;
#pragma unroll
    for (int m = 0; m < 2; m++)
#pragma unroll
        for (int f = 0; f < 4; f++)
#pragma unroll
            for (int j = 0; j < 4; j++) {
                int row = wv * 32 + m * 16 + kg * 4 + j;
                int col = nb + f * 16 + r;
                dst[(size_t)row * FC1_OUT + col] = acc[m][f][j];
            }
}

// reduce split-K + bias + ReLU -> bf16 activations for FC2
__global__ __launch_bounds__(256) void k_reduce1(const float* __restrict__ part,
                                                 const float* __restrict__ bias,
                                                 short* __restrict__ Ab2) {
    int idx = blockIdx.x * 256 + threadIdx.x;
    int o = idx & (FC1_OUT - 1);
    float s = bias[o];
#pragma unroll
    for (int sp = 0; sp < KSPL1; sp++) s += part[(size_t)sp * BATCH * FC1_OUT + idx];
    Ab2[idx] = f2bf(fmaxf(s, 0.f));
}

// ---------------- FC2 MFMA GEMM, B read directly from f32 fc4W ----------------
#define KSPL2 8
#define KCH2  (FC1_OUT / KSPL2)  // 256
__global__ __launch_bounds__(256) void k_gemm2f(const short* __restrict__ Ab,
                                                const float* __restrict__ fc4W,
                                                float* __restrict__ part) {
    int lane = threadIdx.x & 63, wv = threadIdx.x >> 6;
    int r = lane & 15, kg = lane >> 4;
    int nb = blockIdx.x * 16, sp = blockIdx.y;

    f32x4 acc[2] = {};
    const short* a0 = Ab + (size_t)(wv * 32 + r) * FC1_OUT;
    const short* a1 = a0 + (size_t)16 * FC1_OUT;
    int col = nb + r;
    int colc = (col < FC2_OUT) ? col : FC2_OUT - 1;  // clamp; pad cols never read

    int k0 = sp * KCH2 + kg * 8;
    const float* wp = fc4W + (size_t)k0 * FC2_OUT + colc;
#pragma unroll 1
    for (int s = 0; s < KCH2 / 32; s++, k0 += 32) {
        short8 av0 = *(const short8*)(a0 + k0);
        short8 av1 = *(const short8*)(a1 + k0);
        float wf[8];
#pragma unroll
        for (int i = 0; i < 8; i++) wf[i] = wp[(size_t)i * FC2_OUT];
        i32x4 pk;
        pk[0] = cvtpk(wf[0], wf[1]);
        pk[1] = cvtpk(wf[2], wf[3]);
        pk[2] = cvtpk(wf[4], wf[5]);
        pk[3] = cvtpk(wf[6], wf[7]);
        short8 bv = __builtin_bit_cast(short8, pk);
        acc[0] = __builtin_amdgcn_mfma_f32_16x16x32_bf16(av0, bv, acc[0], 0, 0, 0);
        acc[1] = __builtin_amdgcn_mfma_f32_16x16x32_bf16(av1, bv, acc[1], 0, 0, 0);
        wp += (size_t)32 * FC2_OUT;
    }

    float* dst = part + (size_t)sp * BATCH * NP2;
#pragma unroll
    for (int m = 0; m < 2; m++)
#pragma unroll
        for (int j = 0; j < 4; j++) {
            int row = wv * 32 + m * 16 + kg * 4 + j;
            dst[(size_t)row * NP2 + col] = acc[m][j];
        }
}

__global__ __launch_bounds__(256) void k_reduce2(const float* __restrict__ part,
                                                 const float* __restrict__ bias,
                                                 float* __restrict__ out) {
    int idx = blockIdx.x * 256 + threadIdx.x;
    if (idx >= BATCH * NP2) return;
    int b = idx / NP2, o = idx % NP2;
    float s = 0.f;
#pragma unroll
    for (int sp = 0; sp < KSPL2; sp++) s += part[(size_t)sp * BATCH * NP2 + idx];
    if (o < FC2_OUT) out[(size_t)b * FC2_OUT + o] = s + bias[o];
}

extern "C" void kernel_launch(void* const* d_in, const int* in_sizes, int n_in,
                              void* d_out, int out_size, void* d_ws, size_t ws_size,
                              hipStream_t stream) {
    const float* data_x = (const float*)d_in[0];
    const int* ei = (const int*)d_in[1];
    const float* ew = (const float*)d_in[2];
    const float* tc1w1 = (const float*)d_in[3];
    const float* tc1b1 = (const float*)d_in[4];
    const float* tc1w2 = (const float*)d_in[5];
    const float* tc1b2 = (const float*)d_in[6];
    const float* tc1w3 = (const float*)d_in[7];
    const float* tc1b3 = (const float*)d_in[8];
    const float* W0 = (const float*)d_in[9];
    const float* gb0 = (const float*)d_in[10];
    const float* bn0g = (const float*)d_in[11];
    const float* bn0b = (const float*)d_in[12];
    const float* W1 = (const float*)d_in[13];
    const float* gb1 = (const float*)d_in[14];
    const float* bn1g = (const float*)d_in[15];
    const float* bn1b = (const float*)d_in[16];
    const float* tc2w1 = (const float*)d_in[17];
    const float* tc2b1 = (const float*)d_in[18];
    const float* tc2w2 = (const float*)d_in[19];
    const float* tc2b2 = (const float*)d_in[20];
    const float* tc2w3 = (const float*)d_in[21];
    const float* tc2b3 = (const float*)d_in[22];
    const float* bn2g = (const float*)d_in[23];
    const float* bn2b = (const float*)d_in[24];
    const float* fcW = (const float*)d_in[25];
    const float* fcb = (const float*)d_in[26];
    const float* fc4W = (const float*)d_in[27];
    const float* fc4b = (const float*)d_in[28];
    float* out = (float*)d_out;

    char* ws = (char*)d_ws;
    // persistent: x2t (transposed gfeat, written by gatherBT) + Ab
    float* x2t = (float*)(ws + 0);                 // 9,961,472 B
    short* Ab = (short*)(ws + 9961472);            // 1,638,400 B
    const size_t ARENA = 9961472 + 1638400;        // 11,599,872

    // arena A (graph phase)
    size_t off = ARENA;
    auto alloc = [&](size_t bytes) -> void* {
        void* p = ws + off;
        off = (off + bytes + 255) & ~(size_t)255;
        return p;
    };
    unsigned* bucket = (unsigned*)alloc((size_t)NN * BCAP * 4);  // 9.96 MB packed
    int* cnt = (int*)alloc((size_t)NN * 4);
    float* dinv = (float*)alloc((size_t)NN * 4);
    unsigned short* Xb = (unsigned short*)alloc((size_t)NN * 32 * 2);  // 2.5 MB
    unsigned short* h1 = (unsigned short*)alloc((size_t)NN * HID * 2); // 5 MB

    // arena C (FC phase) — overlaps arena A, used only after temporal
    off = ARENA;
    float* part1 = (float*)alloc((size_t)KSPL1 * BATCH * FC1_OUT * 4);
    short* Ab2 = (short*)alloc((size_t)BATCH * FC1_OUT * 2);
    float* part2 = (float*)alloc((size_t)KSPL2 * BATCH * NP2 * 4);
    (void)ws_size; (void)in_sizes; (void)n_in; (void)out_size;

    // ---- bucketed edge build (packed u32 entries) ----
    hipMemsetAsync(cnt, 0, (size_t)NN * 4, stream);
    k_bucket<<<(NE + 255) / 256, 256, 0, stream>>>(ei, ew, cnt, bucket);

    // ---- GCN (gatherBT writes the gfeat transpose directly) ----
    k_cvtX<<<NN / 8, 256, 0, stream>>>(data_x, cnt, bucket, Xb, dinv);
    k_gather20<<<NN / 4, 256, 0, stream>>>(cnt, bucket, dinv, Xb, W0, gb0, bn0g,
                                           bn0b, W1, h1);
    k_gatherBT<<<NN / 4, 256, 0, stream>>>(cnt, bucket, dinv, h1, gb1, bn1g, bn1b,
                                           x2t);

    // ---- temporal (rolling-window, packed fp32; gfeat via x2t) ----
    hipMemsetAsync(Ab, 0, (size_t)BATCH * KP1 * 2, stream);  // zero K-padding
    k_temporal2<<<NN / 16, 256, 0, stream>>>(data_x, x2t, tc1w1, tc1b1, tc1w2, tc1b2,
                                             tc1w3, tc1b3, tc2w1, tc2b1, tc2w2, tc2b2,
                                             tc2w3, tc2b3, bn2g, bn2b, Ab);

    // ---- FC (bf16 MFMA, packed-convert B) ----
    {
        dim3 g(FC1_OUT / 64, KSPL1);
        k_gemm1f<<<g, 256, 0, stream>>>(Ab, fcW, part1);
    }
    k_reduce1<<<BATCH * FC1_OUT / 256, 256, 0, stream>>>(part1, fcb, Ab2);
    {
        dim3 g(NP2 / 16, KSPL2);
        k_gemm2f<<<g, 256, 0, stream>>>(Ab2, fc4W, part2);
    }
    k_reduce2<<<(BATCH * NP2 + 255) / 256, 256, 0, stream>>>(part2, fc4b, out);
}